// Round 3
// baseline (625.363 us; speedup 1.0000x reference)
//
#include <hip/hip_runtime.h>
#include <math.h>

#define D_MODEL 1024
#define NHEAD   16
#define DKH     64
#define DFF_    4096
#define BB      2
#define SS      2048
#define MTOT    (BB*SS)
#define EPSLN   1e-6f
#define NEG_SLOPE 0.01f

typedef unsigned short u16;
typedef unsigned int   u32;
typedef __bf16 bf16x8 __attribute__((ext_vector_type(8)));
typedef float  f32x4  __attribute__((ext_vector_type(4)));
typedef u16    u16x4  __attribute__((ext_vector_type(4)));

__device__ __forceinline__ u16 f2bf(float f) {
    u32 u = __float_as_uint(f);
    u = (u + 0x7fffu + ((u >> 16) & 1u)) >> 16;
    return (u16)u;
}
__device__ __forceinline__ float bf2f(u16 u) {
    return __uint_as_float(((u32)u) << 16);
}

__device__ __forceinline__ void gload_lds16(const u16* g, u16* l) {
    __builtin_amdgcn_global_load_lds(
        (const __attribute__((address_space(1))) u32*)g,
        (__attribute__((address_space(3))) u32*)l,
        16, 0, 0);
}

// ---------------------------------------------------------------------------
// fp32 -> bf16 plain convert
// ---------------------------------------------------------------------------
__global__ __launch_bounds__(256)
void f32_to_bf16(const float* __restrict__ in, u16* __restrict__ out) {
    int i = blockIdx.x * 256 + threadIdx.x;
    float4 v = ((const float4*)in)[i];
    u16x4 o = { f2bf(v.x), f2bf(v.y), f2bf(v.z), f2bf(v.w) };
    ((u16x4*)out)[i] = o;
}

// ---------------------------------------------------------------------------
// W [K][N] fp32 -> WT [N][K] bf16 * scale  (rows offset by out_row_off)
// ---------------------------------------------------------------------------
__global__ __launch_bounds__(256)
void transpose_w_bf16(const float* __restrict__ W, u16* __restrict__ WT,
                      int K, int N, int out_stride, int out_row_off, float scale)
{
    __shared__ u16 T[64 * 72];
    const int t  = threadIdx.x;
    const int n0 = blockIdx.x * 64;
    const int k0 = blockIdx.y * 64;
    #pragma unroll
    for (int i = 0; i < 4; ++i) {
        int r = i * 16 + (t >> 4);          // k
        int c = (t & 15) * 4;               // n
        float4 v = *(const float4*)&W[(size_t)(k0 + r) * N + n0 + c];
        T[(c + 0) * 72 + r] = f2bf(v.x * scale);
        T[(c + 1) * 72 + r] = f2bf(v.y * scale);
        T[(c + 2) * 72 + r] = f2bf(v.z * scale);
        T[(c + 3) * 72 + r] = f2bf(v.w * scale);
    }
    __syncthreads();
    #pragma unroll
    for (int i = 0; i < 4; ++i) {
        int nr = i * 16 + (t >> 4);
        int kc = (t & 15) * 4;
        u16x4 o = { T[nr*72 + kc], T[nr*72 + kc + 1], T[nr*72 + kc + 2], T[nr*72 + kc + 3] };
        *(u16x4*)&WT[(size_t)(out_row_off + n0 + nr) * out_stride + k0 + kc] = o;
    }
}

// ---------------------------------------------------------------------------
// V part of QKV [4096][3072] (cols 2048+) -> Vt [B*H*64][S] bf16
// ---------------------------------------------------------------------------
__global__ __launch_bounds__(256)
void transpose_v(const u16* __restrict__ QKV, u16* __restrict__ Vt)
{
    __shared__ u16 T[64 * 72];
    const int t  = threadIdx.x;
    const int s0 = blockIdx.x * 64;
    const int bh = blockIdx.y;
    const int b  = bh >> 4, h = bh & 15;
    #pragma unroll
    for (int i = 0; i < 2; ++i) {
        int r = i * 32 + (t >> 3);       // s
        int c = (t & 7) * 8;             // d
        bf16x8 v = *(const bf16x8*)(QKV + ((size_t)b * SS + s0 + r) * 3072 + 2048 + h * 64 + c);
        #pragma unroll
        for (int j = 0; j < 8; ++j) T[(c + j) * 72 + r] = ((const u16*)&v)[j];
    }
    __syncthreads();
    #pragma unroll
    for (int i = 0; i < 2; ++i) {
        int d  = i * 32 + (t >> 3);
        int kc = (t & 7) * 8;
        *(bf16x8*)(Vt + ((size_t)bh * 64 + d) * SS + s0 + kc) = *(const bf16x8*)&T[d * 72 + kc];
    }
}

// q-part scaled by log2e/8 (folded attention scale)
__global__ __launch_bounds__(256)
void concat_bias(const float* __restrict__ a, const float* __restrict__ b,
                 const float* __restrict__ c, float* __restrict__ out, float qscale) {
    int i = blockIdx.x * 256 + threadIdx.x;
    out[i] = (i < 1024) ? a[i] * qscale : ((i < 2048) ? b[i - 1024] : c[i - 2048]);
}

// ---------------------------------------------------------------------------
// bf16 MFMA GEMM: C[M,N] = A[M, k_off:k_off+k_len] @ BT[N, ...]^T (+ bias).
// 128x128 tile, BK=32. k_off = blockIdx.z * k_len. EPI: 0 bf16+bias,
// 1 bf16+bias+LeakyReLU, 3 raw f32 (no bias), z-partials at Cout + z*M*N.
// ---------------------------------------------------------------------------
template<int EPI>
__global__ __launch_bounds__(256)
void gemm_bf16(const u16* __restrict__ A, const u16* __restrict__ BT,
               const float* __restrict__ bias, void* __restrict__ Cout,
               int M, int N, int k_len, int kstride)
{
    __shared__ u16 As[128 * 32];
    __shared__ u16 Bs[128 * 32];
    const int tid  = threadIdx.x;
    const int w    = tid >> 6;
    const int lane = tid & 63;
    const int lm   = lane & 15;
    const int lq   = lane >> 4;
    const int row0 = blockIdx.y * 128;
    const int col0 = blockIdx.x * 128;
    const int k_off = blockIdx.z * k_len;
    const int wrow = (w >> 1) * 64;
    const int wcol = (w & 1) * 64;

    f32x4 acc[4][4] = {};

    const int r_l  = lane >> 2;
    const int q_sw = (lane & 3) ^ ((lane >> 3) & 3);
    const u16* a_src = A  + (size_t)(row0 + w * 32 + r_l) * kstride + k_off + q_sw * 8;
    const u16* b_src = BT + (size_t)(col0 + w * 32 + r_l) * kstride + k_off + q_sw * 8;
    u16* a_dst = &As[(w * 32) * 32];
    u16* b_dst = &Bs[(w * 32) * 32];
    const size_t stepA = (size_t)16 * kstride;

    const int pos = lq ^ ((lm >> 1) & 3);
    const u16* a_rd = &As[(wrow + lm) * 32 + pos * 8];
    const u16* b_rd = &Bs[(wcol + lm) * 32 + pos * 8];

    for (int k0 = 0; k0 < k_len; k0 += 32) {
        gload_lds16(a_src + k0,         a_dst);
        gload_lds16(a_src + k0 + stepA, a_dst + 16 * 32);
        gload_lds16(b_src + k0,         b_dst);
        gload_lds16(b_src + k0 + stepA, b_dst + 16 * 32);
        __syncthreads();
        bf16x8 av[4], bv[4];
        #pragma unroll
        for (int m = 0; m < 4; ++m) av[m] = *(const bf16x8*)(a_rd + m * 16 * 32);
        #pragma unroll
        for (int n = 0; n < 4; ++n) bv[n] = *(const bf16x8*)(b_rd + n * 16 * 32);
        #pragma unroll
        for (int m = 0; m < 4; ++m)
            #pragma unroll
            for (int n = 0; n < 4; ++n)
                acc[m][n] = __builtin_amdgcn_mfma_f32_16x16x32_bf16(av[m], bv[n], acc[m][n], 0, 0, 0);
        __syncthreads();
    }

    float bz[4] = {0.f, 0.f, 0.f, 0.f};
    if (EPI != 3) {
        #pragma unroll
        for (int n = 0; n < 4; ++n) bz[n] = bias[col0 + wcol + n * 16 + lm];
    }
    float* Cz = (float*)Cout + (size_t)blockIdx.z * M * N;

    #pragma unroll
    for (int m = 0; m < 4; ++m) {
        #pragma unroll
        for (int e = 0; e < 4; ++e) {
            int row = row0 + wrow + m * 16 + lq * 4 + e;
            #pragma unroll
            for (int n = 0; n < 4; ++n) {
                int col = col0 + wcol + n * 16 + lm;
                float v = acc[m][n][e] + bz[n];
                if (EPI == 1) v = v > 0.f ? v : NEG_SLOPE * v;
                if (EPI == 3) Cz[(size_t)row * N + col] = v;
                else          ((u16*)Cout)[(size_t)row * N + col] = f2bf(v);
            }
        }
    }
}

// ---------------------------------------------------------------------------
// Flash attention, bf16 MFMA, no-max softmax (scores bounded; scale folded
// into Q at weight-transpose time, base-2 exp). Row sums via ones-MFMA.
// K/V fragments read directly from global (L1/L2-resident tiles).
// Only LDS use: Q staging (once) + double-buffered P round-trip.
// ---------------------------------------------------------------------------
__global__ __launch_bounds__(256)
void attn_mfma(const u16* __restrict__ QKV, const u16* __restrict__ Vt,
               u16* __restrict__ ctx)
{
    __shared__ u16 Qs[64 * 72];
    __shared__ u16 Ps[2][64 * 72];
    const int tid = threadIdx.x, w = tid >> 6, lane = tid & 63;
    const int lm = lane & 15, lq = lane >> 4;
    const int q0 = blockIdx.x * 64;
    const int bh = blockIdx.y;
    const int b  = bh >> 4, h = bh & 15;
    const size_t row_b = (size_t)b * SS;
    const int ccol = h * DKH;

    const int sr = tid >> 3;          // 0..31
    const int sc = (tid & 7) * 8;     // 0..56
    #pragma unroll
    for (int i = 0; i < 2; ++i) {
        int r = i * 32 + sr;
        *(bf16x8*)&Qs[r * 72 + sc] =
            *(const bf16x8*)(QKV + (row_b + q0 + r) * 3072 + ccol + sc);
    }
    __syncthreads();
    bf16x8 aq0 = *(const bf16x8*)&Qs[(w * 16 + lm) * 72 + lq * 8];
    bf16x8 aq1 = *(const bf16x8*)&Qs[(w * 16 + lm) * 72 + 32 + lq * 8];

    bf16x8 ones;
    #pragma unroll
    for (int j = 0; j < 8; ++j) ones[j] = (__bf16)1.0f;

    f32x4 o[4] = {};
    f32x4 lacc = {};

    const u16* kbase = QKV + 1024 + ccol + lq * 8;
    const u16* vbase = Vt + ((size_t)bh * 64) * SS + lq * 8;

    for (int kt = 0; kt < SS / 64; ++kt) {
        const int k0 = kt * 64;
        // K fragments direct from global: B[k=d][col=key]
        bf16x8 kf0[4], kf1[4];
        #pragma unroll
        for (int n = 0; n < 4; ++n) {
            const u16* kp = kbase + (row_b + k0 + n * 16 + lm) * 3072;
            kf0[n] = *(const bf16x8*)(kp);
            kf1[n] = *(const bf16x8*)(kp + 32);
        }
        // V fragments direct from global (issued early, consumed after barrier)
        bf16x8 vf0[4], vf1[4];
        #pragma unroll
        for (int n = 0; n < 4; ++n) {
            const u16* vp = vbase + (size_t)(n * 16 + lm) * SS + k0;
            vf0[n] = *(const bf16x8*)(vp);
            vf1[n] = *(const bf16x8*)(vp + 32);
        }
        f32x4 s[4] = {};
        #pragma unroll
        for (int n = 0; n < 4; ++n) {
            s[n] = __builtin_amdgcn_mfma_f32_16x16x32_bf16(aq0, kf0[n], s[n], 0, 0, 0);
            s[n] = __builtin_amdgcn_mfma_f32_16x16x32_bf16(aq1, kf1[n], s[n], 0, 0, 0);
        }
        // P = 2^S (no max subtraction needed: |S·log2e/8| small by construction)
        u16* ps = Ps[kt & 1];
        const int prow = (w * 16 + lq * 4) * 72 + lm;
        #pragma unroll
        for (int n = 0; n < 4; ++n)
            #pragma unroll
            for (int e = 0; e < 4; ++e)
                ps[prow + e * 72 + n * 16] = f2bf(__builtin_exp2f(s[n][e]));
        __syncthreads();
        bf16x8 ap0 = *(const bf16x8*)&ps[(w * 16 + lm) * 72 + lq * 8];
        bf16x8 ap1 = *(const bf16x8*)&ps[(w * 16 + lm) * 72 + 32 + lq * 8];
        #pragma unroll
        for (int n = 0; n < 4; ++n) {
            o[n] = __builtin_amdgcn_mfma_f32_16x16x32_bf16(ap0, vf0[n], o[n], 0, 0, 0);
            o[n] = __builtin_amdgcn_mfma_f32_16x16x32_bf16(ap1, vf1[n], o[n], 0, 0, 0);
        }
        lacc = __builtin_amdgcn_mfma_f32_16x16x32_bf16(ap0, ones, lacc, 0, 0, 0);
        lacc = __builtin_amdgcn_mfma_f32_16x16x32_bf16(ap1, ones, lacc, 0, 0, 0);
    }

    #pragma unroll
    for (int e = 0; e < 4; ++e) {
        float inv = 1.0f / lacc[e];
        int row = q0 + w * 16 + lq * 4 + e;
        u16* dst = ctx + (row_b + row) * D_MODEL + ccol;
        #pragma unroll
        for (int n = 0; n < 4; ++n)
            dst[n * 16 + lm] = f2bf(o[n][e] * inv);
    }
}

// ---------------------------------------------------------------------------
// out = LayerNorm(C0 + C1 + cbias + resid) * g + beta  (+ optional bf16 copy)
// ---------------------------------------------------------------------------
template<int DUAL>
__global__ __launch_bounds__(256)
void add_ln(const float* __restrict__ C0, const float* __restrict__ C1,
            const float* __restrict__ cbias, const float* __restrict__ resid,
            const float* __restrict__ g, const float* __restrict__ beta,
            float* __restrict__ out, u16* __restrict__ out_bf)
{
    __shared__ float red[8];
    const int row = blockIdx.x;
    const int tid = threadIdx.x;
    float4 v0 = ((const float4*)(C0 + (size_t)row * D_MODEL))[tid];
    float4 v1 = ((const float4*)(C1 + (size_t)row * D_MODEL))[tid];
    float4 cb = ((const float4*)cbias)[tid];
    float4 vr = ((const float4*)(resid + (size_t)row * D_MODEL))[tid];
    float4 v  = { v0.x + v1.x + cb.x + vr.x, v0.y + v1.y + cb.y + vr.y,
                  v0.z + v1.z + cb.z + vr.z, v0.w + v1.w + cb.w + vr.w };
    float s  = v.x + v.y + v.z + v.w;
    float sq = v.x*v.x + v.y*v.y + v.z*v.z + v.w*v.w;
    #pragma unroll
    for (int off = 32; off > 0; off >>= 1) {
        s  += __shfl_down(s,  off, 64);
        sq += __shfl_down(sq, off, 64);
    }
    const int wv = tid >> 6;
    if ((tid & 63) == 0) { red[wv] = s; red[4 + wv] = sq; }
    __syncthreads();
    float st  = red[0] + red[1] + red[2] + red[3];
    float sqt = red[4] + red[5] + red[6] + red[7];
    float mu   = st * (1.0f / D_MODEL);
    float var  = sqt * (1.0f / D_MODEL) - mu * mu;
    float rstd = rsqrtf(var + EPSLN);
    float4 gv = ((const float4*)g)[tid];
    float4 bt = ((const float4*)beta)[tid];
    float4 ov;
    ov.x = (v.x - mu) * rstd * gv.x + bt.x;
    ov.y = (v.y - mu) * rstd * gv.y + bt.y;
    ov.z = (v.z - mu) * rstd * gv.z + bt.z;
    ov.w = (v.w - mu) * rstd * gv.w + bt.w;
    ((float4*)(out + (size_t)row * D_MODEL))[tid] = ov;
    if (DUAL) {
        u16x4 ob = { f2bf(ov.x), f2bf(ov.y), f2bf(ov.z), f2bf(ov.w) };
        ((u16x4*)(out_bf + (size_t)row * D_MODEL))[tid] = ob;
    }
}

// ---------------------------------------------------------------------------
extern "C" void kernel_launch(void* const* d_in, const int* in_sizes, int n_in,
                              void* d_out, int out_size, void* d_ws, size_t ws_size,
                              hipStream_t stream) {
    const float* x     = (const float*)d_in[0];
    const float* wq    = (const float*)d_in[1];
    const float* bq    = (const float*)d_in[2];
    const float* wk    = (const float*)d_in[3];
    const float* bk    = (const float*)d_in[4];
    const float* wv    = (const float*)d_in[5];
    const float* bv    = (const float*)d_in[6];
    const float* wo    = (const float*)d_in[7];
    const float* bo    = (const float*)d_in[8];
    const float* g1    = (const float*)d_in[9];
    const float* b1    = (const float*)d_in[10];
    const float* w_ff1 = (const float*)d_in[11];
    const float* b_ff1 = (const float*)d_in[12];
    const float* w_ff2 = (const float*)d_in[13];
    const float* b_ff2 = (const float*)d_in[14];
    const float* g2    = (const float*)d_in[15];
    const float* b2    = (const float*)d_in[16];
    float* out = (float*)d_out;

    const float qscale = 0.18033688011112042f;   // log2(e) / sqrt(DK)

    char* W = (char*)d_ws;
    u16*   x_bf    = (u16*)(W + 0);             // 8.4 MB (later: ctx)
    u16*   wqkvT   = (u16*)(W + 8388608);       // 6.3 MB
    u16*   woT     = (u16*)(W + 14680064);      // 2.1 MB
    u16*   wff1T   = (u16*)(W + 16777216);      // 8.4 MB
    u16*   wff2T   = (u16*)(W + 25165824);      // 8.4 MB
    u16*   QKV     = (u16*)(W + 33554432);      // 25.2 MB (later: ff1 spans QKV+VtG)
    u16*   VtG     = (u16*)(W + 58720256);      // 8.4 MB
    float* C0      = (float*)(W + 67108864);    // 16.8 MB (o-proj/ff2 partial 0)
    float* C1      = (float*)(W + 83886080);    // 16.8 MB (o-proj/ff2 partial 1)
    float* h_f     = (float*)(W + 100663296);   // 16.8 MB
    u16*   h_bf    = (u16*)(W + 117440512);     // 8.4 MB
    float* qkv_bias= (float*)(W + 125829120);   // 12 KB
    u16*   ctx     = x_bf;
    u16*   ff1_bf  = QKV;

    dim3 blk(256);
    // --- input conversions (Q weight/bias pre-scaled by log2e/8) ---
    f32_to_bf16<<<4096, blk, 0, stream>>>(x, x_bf);
    transpose_w_bf16<<<dim3(16, 16), blk, 0, stream>>>(wq, wqkvT, 1024, 1024, 1024, 0, qscale);
    transpose_w_bf16<<<dim3(16, 16), blk, 0, stream>>>(wk, wqkvT, 1024, 1024, 1024, 1024, 1.0f);
    transpose_w_bf16<<<dim3(16, 16), blk, 0, stream>>>(wv, wqkvT, 1024, 1024, 1024, 2048, 1.0f);
    transpose_w_bf16<<<dim3(16, 16), blk, 0, stream>>>(wo, woT, 1024, 1024, 1024, 0, 1.0f);
    transpose_w_bf16<<<dim3(64, 16), blk, 0, stream>>>(w_ff1, wff1T, 1024, 4096, 1024, 0, 1.0f);
    transpose_w_bf16<<<dim3(16, 64), blk, 0, stream>>>(w_ff2, wff2T, 4096, 1024, 4096, 0, 1.0f);
    concat_bias<<<12, blk, 0, stream>>>(bq, bk, bv, qkv_bias, qscale);

    // --- QKV projection (fused) ---
    gemm_bf16<0><<<dim3(24, 32, 1), blk, 0, stream>>>(x_bf, wqkvT, qkv_bias, QKV, MTOT, 3072, 1024, 1024);
    // --- V transpose per head ---
    transpose_v<<<dim3(32, 32), blk, 0, stream>>>(QKV, VtG);
    // --- attention ---
    attn_mfma<<<dim3(32, 32), blk, 0, stream>>>(QKV, VtG, ctx);
    // --- output projection, split-K=2 (partials; bias folded into LN1) ---
    gemm_bf16<3><<<dim3(8, 32, 2), blk, 0, stream>>>(ctx, woT, nullptr, C0, MTOT, 1024, 512, 1024);
    // --- residual + LN1 ---
    add_ln<1><<<MTOT, blk, 0, stream>>>(C0, C1, bo, x, g1, b1, h_f, h_bf);
    // --- FFN ---
    gemm_bf16<1><<<dim3(32, 32, 1), blk, 0, stream>>>(h_bf, wff1T, b_ff1, ff1_bf, MTOT, DFF_, 1024, 1024);
    gemm_bf16<3><<<dim3(8, 32, 2), blk, 0, stream>>>(ff1_bf, wff2T, nullptr, C0, MTOT, 1024, 2048, 4096);
    // --- residual + LN2 ---
    add_ln<0><<<MTOT, blk, 0, stream>>>(C0, C1, b_ff2, h_f, g2, b2, out, nullptr);
}

// Round 4
// 417.426 us; speedup vs baseline: 1.4981x; 1.4981x over previous
//
#include <hip/hip_runtime.h>
#include <math.h>

#define D_MODEL 1024
#define NHEAD   16
#define DKH     64
#define DFF_    4096
#define BB      2
#define SS      2048
#define MTOT    (BB*SS)
#define EPSLN   1e-6f
#define NEG_SLOPE 0.01f

typedef unsigned short u16;
typedef unsigned int   u32;
typedef __bf16 bf16x8 __attribute__((ext_vector_type(8)));
typedef float  f32x4  __attribute__((ext_vector_type(4)));
typedef u16    u16x4  __attribute__((ext_vector_type(4)));

__device__ __forceinline__ u16 f2bf(float f) {
    u32 u = __float_as_uint(f);
    u = (u + 0x7fffu + ((u >> 16) & 1u)) >> 16;
    return (u16)u;
}

__device__ __forceinline__ void gload_lds16(const u16* g, u16* l) {
    __builtin_amdgcn_global_load_lds(
        (const __attribute__((address_space(1))) u32*)g,
        (__attribute__((address_space(3))) u32*)l,
        16, 0, 0);
}

// ---------------------------------------------------------------------------
// fp32 -> bf16 plain convert
// ---------------------------------------------------------------------------
__global__ __launch_bounds__(256)
void f32_to_bf16(const float* __restrict__ in, u16* __restrict__ out) {
    int i = blockIdx.x * 256 + threadIdx.x;
    float4 v = ((const float4*)in)[i];
    u16x4 o = { f2bf(v.x), f2bf(v.y), f2bf(v.z), f2bf(v.w) };
    ((u16x4*)out)[i] = o;
}

// ---------------------------------------------------------------------------
// W [K][N] fp32 -> WT [N][K] bf16 * scale  (rows offset by out_row_off)
// ---------------------------------------------------------------------------
__global__ __launch_bounds__(256)
void transpose_w_bf16(const float* __restrict__ W, u16* __restrict__ WT,
                      int K, int N, int out_stride, int out_row_off, float scale)
{
    __shared__ u16 T[64 * 72];
    const int t  = threadIdx.x;
    const int n0 = blockIdx.x * 64;
    const int k0 = blockIdx.y * 64;
    #pragma unroll
    for (int i = 0; i < 4; ++i) {
        int r = i * 16 + (t >> 4);          // k
        int c = (t & 15) * 4;               // n
        float4 v = *(const float4*)&W[(size_t)(k0 + r) * N + n0 + c];
        T[(c + 0) * 72 + r] = f2bf(v.x * scale);
        T[(c + 1) * 72 + r] = f2bf(v.y * scale);
        T[(c + 2) * 72 + r] = f2bf(v.z * scale);
        T[(c + 3) * 72 + r] = f2bf(v.w * scale);
    }
    __syncthreads();
    #pragma unroll
    for (int i = 0; i < 4; ++i) {
        int nr = i * 16 + (t >> 4);
        int kc = (t & 15) * 4;
        u16x4 o = { T[nr*72 + kc], T[nr*72 + kc + 1], T[nr*72 + kc + 2], T[nr*72 + kc + 3] };
        *(u16x4*)&WT[(size_t)(out_row_off + n0 + nr) * out_stride + k0 + kc] = o;
    }
}

// ---------------------------------------------------------------------------
// V part of QKV [4096][3072] (cols 2048+) -> Vt [B*H*64][S] bf16
// ---------------------------------------------------------------------------
__global__ __launch_bounds__(256)
void transpose_v(const u16* __restrict__ QKV, u16* __restrict__ Vt)
{
    __shared__ u16 T[64 * 72];
    const int t  = threadIdx.x;
    const int s0 = blockIdx.x * 64;
    const int bh = blockIdx.y;
    const int b  = bh >> 4, h = bh & 15;
    #pragma unroll
    for (int i = 0; i < 2; ++i) {
        int r = i * 32 + (t >> 3);       // s
        int c = (t & 7) * 8;             // d
        bf16x8 v = *(const bf16x8*)(QKV + ((size_t)b * SS + s0 + r) * 3072 + 2048 + h * 64 + c);
        #pragma unroll
        for (int j = 0; j < 8; ++j) T[(c + j) * 72 + r] = ((const u16*)&v)[j];
    }
    __syncthreads();
    #pragma unroll
    for (int i = 0; i < 2; ++i) {
        int d  = i * 32 + (t >> 3);
        int kc = (t & 7) * 8;
        *(bf16x8*)(Vt + ((size_t)bh * 64 + d) * SS + s0 + kc) = *(const bf16x8*)&T[d * 72 + kc];
    }
}

// q-part scaled by log2e/8 (folded attention scale)
__global__ __launch_bounds__(256)
void concat_bias(const float* __restrict__ a, const float* __restrict__ b,
                 const float* __restrict__ c, float* __restrict__ out, float qscale) {
    int i = blockIdx.x * 256 + threadIdx.x;
    out[i] = (i < 1024) ? a[i] * qscale : ((i < 2048) ? b[i - 1024] : c[i - 2048]);
}

// ---------------------------------------------------------------------------
// bf16 MFMA GEMM: C[M,N] = A[M, k_off:k_off+k_len] @ BT[N, ...]^T (+ bias).
// 128x128 tile, BK=32. k_off = blockIdx.z * k_len. EPI: 0 bf16+bias,
// 1 bf16+bias+LeakyReLU, 3 raw f32 (no bias), z-partials at Cout + z*M*N.
// ---------------------------------------------------------------------------
template<int EPI>
__global__ __launch_bounds__(256)
void gemm_bf16(const u16* __restrict__ A, const u16* __restrict__ BT,
               const float* __restrict__ bias, void* __restrict__ Cout,
               int M, int N, int k_len, int kstride)
{
    __shared__ u16 As[128 * 32];
    __shared__ u16 Bs[128 * 32];
    const int tid  = threadIdx.x;
    const int w    = tid >> 6;
    const int lane = tid & 63;
    const int lm   = lane & 15;
    const int lq   = lane >> 4;
    const int row0 = blockIdx.y * 128;
    const int col0 = blockIdx.x * 128;
    const int k_off = blockIdx.z * k_len;
    const int wrow = (w >> 1) * 64;
    const int wcol = (w & 1) * 64;

    f32x4 acc[4][4] = {};

    const int r_l  = lane >> 2;
    const int q_sw = (lane & 3) ^ ((lane >> 3) & 3);
    const u16* a_src = A  + (size_t)(row0 + w * 32 + r_l) * kstride + k_off + q_sw * 8;
    const u16* b_src = BT + (size_t)(col0 + w * 32 + r_l) * kstride + k_off + q_sw * 8;
    u16* a_dst = &As[(w * 32) * 32];
    u16* b_dst = &Bs[(w * 32) * 32];
    const size_t stepA = (size_t)16 * kstride;

    const int pos = lq ^ ((lm >> 1) & 3);
    const u16* a_rd = &As[(wrow + lm) * 32 + pos * 8];
    const u16* b_rd = &Bs[(wcol + lm) * 32 + pos * 8];

    for (int k0 = 0; k0 < k_len; k0 += 32) {
        gload_lds16(a_src + k0,         a_dst);
        gload_lds16(a_src + k0 + stepA, a_dst + 16 * 32);
        gload_lds16(b_src + k0,         b_dst);
        gload_lds16(b_src + k0 + stepA, b_dst + 16 * 32);
        __syncthreads();
        bf16x8 av[4], bv[4];
        #pragma unroll
        for (int m = 0; m < 4; ++m) av[m] = *(const bf16x8*)(a_rd + m * 16 * 32);
        #pragma unroll
        for (int n = 0; n < 4; ++n) bv[n] = *(const bf16x8*)(b_rd + n * 16 * 32);
        #pragma unroll
        for (int m = 0; m < 4; ++m)
            #pragma unroll
            for (int n = 0; n < 4; ++n)
                acc[m][n] = __builtin_amdgcn_mfma_f32_16x16x32_bf16(av[m], bv[n], acc[m][n], 0, 0, 0);
        __syncthreads();
    }

    float bz[4] = {0.f, 0.f, 0.f, 0.f};
    if (EPI != 3) {
        #pragma unroll
        for (int n = 0; n < 4; ++n) bz[n] = bias[col0 + wcol + n * 16 + lm];
    }
    float* Cz = (float*)Cout + (size_t)blockIdx.z * M * N;

    #pragma unroll
    for (int m = 0; m < 4; ++m) {
        #pragma unroll
        for (int e = 0; e < 4; ++e) {
            int row = row0 + wrow + m * 16 + lq * 4 + e;
            #pragma unroll
            for (int n = 0; n < 4; ++n) {
                int col = col0 + wcol + n * 16 + lm;
                float v = acc[m][n][e] + bz[n];
                if (EPI == 1) v = v > 0.f ? v : NEG_SLOPE * v;
                if (EPI == 3) Cz[(size_t)row * N + col] = v;
                else          ((u16*)Cout)[(size_t)row * N + col] = f2bf(v);
            }
        }
    }
}

// ---------------------------------------------------------------------------
// Flash attention, bf16 MFMA. LDS-staged K/V tiles (coalesced) with one-
// iteration VGPR prefetch ahead; no-max exp2 softmax (scale folded into Q
// weights); row sums via ones-MFMA. 3 barriers/iter, 36.9 KB LDS -> 4 blk/CU.
// ---------------------------------------------------------------------------
__global__ __launch_bounds__(256)
void attn_mfma(const u16* __restrict__ QKV, const u16* __restrict__ Vt,
               u16* __restrict__ ctx)
{
    __shared__ u16 Qs[64 * 72];
    __shared__ u16 Ks[64 * 72];
    __shared__ u16 Vs[64 * 72];
    __shared__ u16 Ps[64 * 72];
    const int tid = threadIdx.x, w = tid >> 6, lane = tid & 63;
    const int lm = lane & 15, lq = lane >> 4;
    const int q0 = blockIdx.x * 64;
    const int bh = blockIdx.y;
    const int b  = bh >> 4, h = bh & 15;
    const size_t row_b = (size_t)b * SS;
    const int ccol = h * DKH;

    const int sr = tid >> 3;          // 0..31
    const int sc = (tid & 7) * 8;     // 0..56

    // stage Q once
    #pragma unroll
    for (int i = 0; i < 2; ++i) {
        int r = i * 32 + sr;
        *(bf16x8*)&Qs[r * 72 + sc] =
            *(const bf16x8*)(QKV + (row_b + q0 + r) * 3072 + ccol + sc);
    }
    // prefetch K/V tile 0 into registers
    bf16x8 kr[2], vr[2];
    #pragma unroll
    for (int i = 0; i < 2; ++i) {
        int r = i * 32 + sr;
        kr[i] = *(const bf16x8*)(QKV + (row_b + r) * 3072 + 1024 + ccol + sc);
        vr[i] = *(const bf16x8*)(Vt + ((size_t)bh * 64 + r) * SS + sc);
    }
    __syncthreads();
    bf16x8 aq0 = *(const bf16x8*)&Qs[(w * 16 + lm) * 72 + lq * 8];
    bf16x8 aq1 = *(const bf16x8*)&Qs[(w * 16 + lm) * 72 + 32 + lq * 8];

    bf16x8 ones;
    #pragma unroll
    for (int j = 0; j < 8; ++j) ones[j] = (__bf16)1.0f;

    f32x4 o[4] = {};
    f32x4 lacc = {};

    for (int kt = 0; kt < SS / 64; ++kt) {
        __syncthreads();   // A: all waves done reading Ks/Vs (prev iter)
        #pragma unroll
        for (int i = 0; i < 2; ++i) {
            int r = i * 32 + sr;
            *(bf16x8*)&Ks[r * 72 + sc] = kr[i];
            *(bf16x8*)&Vs[r * 72 + sc] = vr[i];
        }
        // prefetch next tile (wraps on last iter; values unused)
        const int kn = ((kt + 1) & 31) * 64;
        #pragma unroll
        for (int i = 0; i < 2; ++i) {
            int r = i * 32 + sr;
            kr[i] = *(const bf16x8*)(QKV + (row_b + kn + r) * 3072 + 1024 + ccol + sc);
            vr[i] = *(const bf16x8*)(Vt + ((size_t)bh * 64 + r) * SS + kn + sc);
        }
        __syncthreads();   // B: Ks/Vs visible

        f32x4 s[4] = {};
        #pragma unroll
        for (int n = 0; n < 4; ++n) {
            bf16x8 bk0 = *(const bf16x8*)&Ks[(n * 16 + lm) * 72 + lq * 8];
            bf16x8 bk1 = *(const bf16x8*)&Ks[(n * 16 + lm) * 72 + 32 + lq * 8];
            s[n] = __builtin_amdgcn_mfma_f32_16x16x32_bf16(aq0, bk0, s[n], 0, 0, 0);
            s[n] = __builtin_amdgcn_mfma_f32_16x16x32_bf16(aq1, bk1, s[n], 0, 0, 0);
        }
        // P = 2^S (no max subtraction: |S| bounded, scale pre-folded)
        const int prow = (w * 16 + lq * 4) * 72 + lm;
        #pragma unroll
        for (int n = 0; n < 4; ++n)
            #pragma unroll
            for (int e = 0; e < 4; ++e)
                Ps[prow + e * 72 + n * 16] = f2bf(__builtin_exp2f(s[n][e]));
        __syncthreads();   // C: Ps visible

        bf16x8 ap0 = *(const bf16x8*)&Ps[(w * 16 + lm) * 72 + lq * 8];
        bf16x8 ap1 = *(const bf16x8*)&Ps[(w * 16 + lm) * 72 + 32 + lq * 8];
        #pragma unroll
        for (int n = 0; n < 4; ++n) {
            bf16x8 bv0 = *(const bf16x8*)&Vs[(n * 16 + lm) * 72 + lq * 8];
            bf16x8 bv1 = *(const bf16x8*)&Vs[(n * 16 + lm) * 72 + 32 + lq * 8];
            o[n] = __builtin_amdgcn_mfma_f32_16x16x32_bf16(ap0, bv0, o[n], 0, 0, 0);
            o[n] = __builtin_amdgcn_mfma_f32_16x16x32_bf16(ap1, bv1, o[n], 0, 0, 0);
        }
        lacc = __builtin_amdgcn_mfma_f32_16x16x32_bf16(ap0, ones, lacc, 0, 0, 0);
        lacc = __builtin_amdgcn_mfma_f32_16x16x32_bf16(ap1, ones, lacc, 0, 0, 0);
    }

    #pragma unroll
    for (int e = 0; e < 4; ++e) {
        float inv = 1.0f / lacc[e];
        int row = q0 + w * 16 + lq * 4 + e;
        u16* dst = ctx + (row_b + row) * D_MODEL + ccol;
        #pragma unroll
        for (int n = 0; n < 4; ++n)
            dst[n * 16 + lm] = f2bf(o[n][e] * inv);
    }
}

// ---------------------------------------------------------------------------
// out = LayerNorm(C0 + C1 + cbias + resid) * g + beta  (+ optional bf16 copy)
// ---------------------------------------------------------------------------
template<int DUAL>
__global__ __launch_bounds__(256)
void add_ln(const float* __restrict__ C0, const float* __restrict__ C1,
            const float* __restrict__ cbias, const float* __restrict__ resid,
            const float* __restrict__ g, const float* __restrict__ beta,
            float* __restrict__ out, u16* __restrict__ out_bf)
{
    __shared__ float red[8];
    const int row = blockIdx.x;
    const int tid = threadIdx.x;
    float4 v0 = ((const float4*)(C0 + (size_t)row * D_MODEL))[tid];
    float4 v1 = ((const float4*)(C1 + (size_t)row * D_MODEL))[tid];
    float4 cb = ((const float4*)cbias)[tid];
    float4 vr = ((const float4*)(resid + (size_t)row * D_MODEL))[tid];
    float4 v  = { v0.x + v1.x + cb.x + vr.x, v0.y + v1.y + cb.y + vr.y,
                  v0.z + v1.z + cb.z + vr.z, v0.w + v1.w + cb.w + vr.w };
    float s  = v.x + v.y + v.z + v.w;
    float sq = v.x*v.x + v.y*v.y + v.z*v.z + v.w*v.w;
    #pragma unroll
    for (int off = 32; off > 0; off >>= 1) {
        s  += __shfl_down(s,  off, 64);
        sq += __shfl_down(sq, off, 64);
    }
    const int wv = tid >> 6;
    if ((tid & 63) == 0) { red[wv] = s; red[4 + wv] = sq; }
    __syncthreads();
    float st  = red[0] + red[1] + red[2] + red[3];
    float sqt = red[4] + red[5] + red[6] + red[7];
    float mu   = st * (1.0f / D_MODEL);
    float var  = sqt * (1.0f / D_MODEL) - mu * mu;
    float rstd = rsqrtf(var + EPSLN);
    float4 gv = ((const float4*)g)[tid];
    float4 bt = ((const float4*)beta)[tid];
    float4 ov;
    ov.x = (v.x - mu) * rstd * gv.x + bt.x;
    ov.y = (v.y - mu) * rstd * gv.y + bt.y;
    ov.z = (v.z - mu) * rstd * gv.z + bt.z;
    ov.w = (v.w - mu) * rstd * gv.w + bt.w;
    ((float4*)(out + (size_t)row * D_MODEL))[tid] = ov;
    if (DUAL) {
        u16x4 ob = { f2bf(ov.x), f2bf(ov.y), f2bf(ov.z), f2bf(ov.w) };
        ((u16x4*)(out_bf + (size_t)row * D_MODEL))[tid] = ob;
    }
}

// ---------------------------------------------------------------------------
extern "C" void kernel_launch(void* const* d_in, const int* in_sizes, int n_in,
                              void* d_out, int out_size, void* d_ws, size_t ws_size,
                              hipStream_t stream) {
    const float* x     = (const float*)d_in[0];
    const float* wq    = (const float*)d_in[1];
    const float* bq    = (const float*)d_in[2];
    const float* wk    = (const float*)d_in[3];
    const float* bk    = (const float*)d_in[4];
    const float* wv    = (const float*)d_in[5];
    const float* bv    = (const float*)d_in[6];
    const float* wo    = (const float*)d_in[7];
    const float* bo    = (const float*)d_in[8];
    const float* g1    = (const float*)d_in[9];
    const float* b1    = (const float*)d_in[10];
    const float* w_ff1 = (const float*)d_in[11];
    const float* b_ff1 = (const float*)d_in[12];
    const float* w_ff2 = (const float*)d_in[13];
    const float* b_ff2 = (const float*)d_in[14];
    const float* g2    = (const float*)d_in[15];
    const float* b2    = (const float*)d_in[16];
    float* out = (float*)d_out;

    const float qscale = 0.18033688011112042f;   // log2(e) / sqrt(DK)

    char* W = (char*)d_ws;
    u16*   x_bf    = (u16*)(W + 0);             // 8.4 MB (later: ctx)
    u16*   wqkvT   = (u16*)(W + 8388608);       // 6.3 MB
    u16*   woT     = (u16*)(W + 14680064);      // 2.1 MB
    u16*   wff1T   = (u16*)(W + 16777216);      // 8.4 MB
    u16*   wff2T   = (u16*)(W + 25165824);      // 8.4 MB
    u16*   QKV     = (u16*)(W + 33554432);      // 25.2 MB (later: ff1 spans QKV+VtG)
    u16*   VtG     = (u16*)(W + 58720256);      // 8.4 MB
    float* C0      = (float*)(W + 67108864);    // 16.8 MB (o-proj/ff2 partial 0)
    float* C1      = (float*)(W + 83886080);    // 16.8 MB (o-proj/ff2 partial 1)
    float* h_f     = (float*)(W + 100663296);   // 16.8 MB
    u16*   h_bf    = (u16*)(W + 117440512);     // 8.4 MB
    float* qkv_bias= (float*)(W + 125829120);   // 12 KB
    u16*   ctx     = x_bf;
    u16*   ff1_bf  = QKV;

    dim3 blk(256);
    // --- input conversions (Q weight/bias pre-scaled by log2e/8) ---
    f32_to_bf16<<<4096, blk, 0, stream>>>(x, x_bf);
    transpose_w_bf16<<<dim3(16, 16), blk, 0, stream>>>(wq, wqkvT, 1024, 1024, 1024, 0, qscale);
    transpose_w_bf16<<<dim3(16, 16), blk, 0, stream>>>(wk, wqkvT, 1024, 1024, 1024, 1024, 1.0f);
    transpose_w_bf16<<<dim3(16, 16), blk, 0, stream>>>(wv, wqkvT, 1024, 1024, 1024, 2048, 1.0f);
    transpose_w_bf16<<<dim3(16, 16), blk, 0, stream>>>(wo, woT, 1024, 1024, 1024, 0, 1.0f);
    transpose_w_bf16<<<dim3(64, 16), blk, 0, stream>>>(w_ff1, wff1T, 1024, 4096, 1024, 0, 1.0f);
    transpose_w_bf16<<<dim3(16, 64), blk, 0, stream>>>(w_ff2, wff2T, 4096, 1024, 4096, 0, 1.0f);
    concat_bias<<<12, blk, 0, stream>>>(bq, bk, bv, qkv_bias, qscale);

    // --- QKV projection (fused) ---
    gemm_bf16<0><<<dim3(24, 32, 1), blk, 0, stream>>>(x_bf, wqkvT, qkv_bias, QKV, MTOT, 3072, 1024, 1024);
    // --- V transpose per head ---
    transpose_v<<<dim3(32, 32), blk, 0, stream>>>(QKV, VtG);
    // --- attention ---
    attn_mfma<<<dim3(32, 32), blk, 0, stream>>>(QKV, VtG, ctx);
    // --- output projection, split-K=2 (partials; bias folded into LN1) ---
    gemm_bf16<3><<<dim3(8, 32, 2), blk, 0, stream>>>(ctx, woT, nullptr, C0, MTOT, 1024, 512, 1024);
    // --- residual + LN1 ---
    add_ln<1><<<MTOT, blk, 0, stream>>>(C0, C1, bo, x, g1, b1, h_f, h_bf);
    // --- FFN ---
    gemm_bf16<1><<<dim3(32, 32, 1), blk, 0, stream>>>(h_bf, wff1T, b_ff1, ff1_bf, MTOT, DFF_, 1024, 1024);
    gemm_bf16<3><<<dim3(8, 32, 2), blk, 0, stream>>>(ff1_bf, wff2T, nullptr, C0, MTOT, 1024, 2048, 4096);
    // --- residual + LN2 ---
    add_ln<0><<<MTOT, blk, 0, stream>>>(C0, C1, b_ff2, h_f, g2, b2, out, nullptr);
}

// Round 5
// 386.499 us; speedup vs baseline: 1.6180x; 1.0800x over previous
//
#include <hip/hip_runtime.h>
#include <math.h>

#define D_MODEL 1024
#define NHEAD   16
#define DKH     64
#define DFF_    4096
#define BB      2
#define SS      2048
#define MTOT    (BB*SS)
#define EPSLN   1e-6f
#define NEG_SLOPE 0.01f

typedef unsigned short u16;
typedef unsigned int   u32;
typedef __bf16 bf16x8 __attribute__((ext_vector_type(8)));
typedef float  f32x4  __attribute__((ext_vector_type(4)));
typedef u16    u16x4  __attribute__((ext_vector_type(4)));

__device__ __forceinline__ u16 f2bf(float f) {
    u32 u = __float_as_uint(f);
    u = (u + 0x7fffu + ((u >> 16) & 1u)) >> 16;
    return (u16)u;
}
__device__ __forceinline__ float bf2f(u16 u) {
    return __uint_as_float(((u32)u) << 16);
}

__device__ __forceinline__ void gload_lds16(const u16* g, u16* l) {
    __builtin_amdgcn_global_load_lds(
        (const __attribute__((address_space(1))) u32*)g,
        (__attribute__((address_space(3))) u32*)l,
        16, 0, 0);
}

// ---------------------------------------------------------------------------
// 64x64 fp32->bf16 transpose tile (device helper for prep kernel)
// ---------------------------------------------------------------------------
__device__ __forceinline__ void transpose_tile(const float* __restrict__ W,
        u16* __restrict__ WT, int N, int out_stride, int out_row_off,
        float scale, int bx, int by, u16* T)
{
    const int t  = threadIdx.x;
    const int n0 = bx * 64;
    const int k0 = by * 64;
    #pragma unroll
    for (int i = 0; i < 4; ++i) {
        int r = i * 16 + (t >> 4);          // k
        int c = (t & 15) * 4;               // n
        float4 v = *(const float4*)&W[(size_t)(k0 + r) * N + n0 + c];
        T[(c + 0) * 72 + r] = f2bf(v.x * scale);
        T[(c + 1) * 72 + r] = f2bf(v.y * scale);
        T[(c + 2) * 72 + r] = f2bf(v.z * scale);
        T[(c + 3) * 72 + r] = f2bf(v.w * scale);
    }
    __syncthreads();
    #pragma unroll
    for (int i = 0; i < 4; ++i) {
        int nr = i * 16 + (t >> 4);
        int kc = (t & 15) * 4;
        u16x4 o = { T[nr*72 + kc], T[nr*72 + kc + 1], T[nr*72 + kc + 2], T[nr*72 + kc + 3] };
        *(u16x4*)&WT[(size_t)(out_row_off + n0 + nr) * out_stride + k0 + kc] = o;
    }
}

// ---------------------------------------------------------------------------
// Fused prep: x f32->bf16 | 4 square W transposes | ff1 | ff2 | bias concat.
// Block ranges: [0,4096) x | [4096,5120) wq/wk/wv/wo | [5120,6144) ff1 |
// [6144,7168) ff2 | [7168,7180) bias.
// ---------------------------------------------------------------------------
__global__ __launch_bounds__(256)
void prep(const float* __restrict__ x, u16* __restrict__ x_bf,
          const float* __restrict__ wq, const float* __restrict__ wk,
          const float* __restrict__ wv, const float* __restrict__ wo,
          const float* __restrict__ wff1, const float* __restrict__ wff2,
          u16* __restrict__ wqkvT, u16* __restrict__ woT,
          u16* __restrict__ wff1T, u16* __restrict__ wff2T,
          const float* __restrict__ bq, const float* __restrict__ bk,
          const float* __restrict__ bv, float* __restrict__ qkv_bias,
          float qscale)
{
    __shared__ u16 T[64 * 72];
    int blk = blockIdx.x;
    if (blk < 4096) {
        int i = blk * 256 + threadIdx.x;
        float4 v = ((const float4*)x)[i];
        u16x4 o = { f2bf(v.x), f2bf(v.y), f2bf(v.z), f2bf(v.w) };
        ((u16x4*)x_bf)[i] = o;
        return;
    }
    blk -= 4096;
    if (blk < 1024) {   // wq/wk/wv/wo, 256 blocks each (16x16 tiles)
        int which = blk >> 8, r = blk & 255;
        const float* Ws = which == 0 ? wq : which == 1 ? wk : which == 2 ? wv : wo;
        u16* Wd   = which == 3 ? woT : wqkvT;
        int off   = which == 3 ? 0 : which * 1024;
        float sc  = which == 0 ? qscale : 1.0f;
        transpose_tile(Ws, Wd, 1024, 1024, off, sc, r & 15, r >> 4, T);
        return;
    }
    blk -= 1024;
    if (blk < 1024) {   // w_ff1 [1024][4096]: 64 n-tiles x 16 k-tiles
        transpose_tile(wff1, wff1T, 4096, 1024, 0, 1.0f, blk & 63, blk >> 6, T);
        return;
    }
    blk -= 1024;
    if (blk < 1024) {   // w_ff2 [4096][1024]: 16 n-tiles x 64 k-tiles
        transpose_tile(wff2, wff2T, 1024, 4096, 0, 1.0f, blk & 15, blk >> 4, T);
        return;
    }
    blk -= 1024;        // 12 blocks: bias concat (q scaled)
    int i = blk * 256 + threadIdx.x;
    qkv_bias[i] = (i < 1024) ? bq[i] * qscale
                : (i < 2048) ? bk[i - 1024] : bv[i - 2048];
}

// ---------------------------------------------------------------------------
// bf16 MFMA GEMM: C[M,N] = A[M, k_off:+k_len] @ BT[N,...]^T (+ bias).
// 128x128 tile, BK=32, global_load_lds w/ XOR swizzle.
// EPI: 1 = bf16 + bias + LeakyReLU
//      3 = bf16 partials (no bias) at Cout + z*M*N
//      4 = QKV special: cols <2048 normal bf16+bias into QKV (N=3072);
//          cols >=2048 (V) written transposed into Vt[bh*64+d][SS]
// ---------------------------------------------------------------------------
template<int EPI>
__global__ __launch_bounds__(256)
void gemm_bf16(const u16* __restrict__ A, const u16* __restrict__ BT,
               const float* __restrict__ bias, void* __restrict__ Cout,
               u16* __restrict__ Vt, int M, int N, int k_len, int kstride)
{
    __shared__ u16 As[128 * 32];
    __shared__ u16 Bs[128 * 32];
    const int tid  = threadIdx.x;
    const int w    = tid >> 6;
    const int lane = tid & 63;
    const int lm   = lane & 15;
    const int lq   = lane >> 4;
    const int row0 = blockIdx.y * 128;
    const int col0 = blockIdx.x * 128;
    const int k_off = blockIdx.z * k_len;
    const int wrow = (w >> 1) * 64;
    const int wcol = (w & 1) * 64;

    f32x4 acc[4][4] = {};

    const int r_l  = lane >> 2;
    const int q_sw = (lane & 3) ^ ((lane >> 3) & 3);
    const u16* a_src = A  + (size_t)(row0 + w * 32 + r_l) * kstride + k_off + q_sw * 8;
    const u16* b_src = BT + (size_t)(col0 + w * 32 + r_l) * kstride + k_off + q_sw * 8;
    u16* a_dst = &As[(w * 32) * 32];
    u16* b_dst = &Bs[(w * 32) * 32];
    const size_t stepA = (size_t)16 * kstride;

    const int pos = lq ^ ((lm >> 1) & 3);
    const u16* a_rd = &As[(wrow + lm) * 32 + pos * 8];
    const u16* b_rd = &Bs[(wcol + lm) * 32 + pos * 8];

    for (int k0 = 0; k0 < k_len; k0 += 32) {
        gload_lds16(a_src + k0,         a_dst);
        gload_lds16(a_src + k0 + stepA, a_dst + 16 * 32);
        gload_lds16(b_src + k0,         b_dst);
        gload_lds16(b_src + k0 + stepA, b_dst + 16 * 32);
        __syncthreads();
        bf16x8 av[4], bv[4];
        #pragma unroll
        for (int m = 0; m < 4; ++m) av[m] = *(const bf16x8*)(a_rd + m * 16 * 32);
        #pragma unroll
        for (int n = 0; n < 4; ++n) bv[n] = *(const bf16x8*)(b_rd + n * 16 * 32);
        #pragma unroll
        for (int m = 0; m < 4; ++m)
            #pragma unroll
            for (int n = 0; n < 4; ++n)
                acc[m][n] = __builtin_amdgcn_mfma_f32_16x16x32_bf16(av[m], bv[n], acc[m][n], 0, 0, 0);
        __syncthreads();
    }

    float bz[4] = {0.f, 0.f, 0.f, 0.f};
    if (EPI != 3) {
        #pragma unroll
        for (int n = 0; n < 4; ++n) bz[n] = bias[col0 + wcol + n * 16 + lm];
    }

    if (EPI == 4 && col0 >= 2048) {
        // V part -> Vt[(b*16+h)*64 + d][2048], 4 consecutive s per store
        #pragma unroll
        for (int m = 0; m < 4; ++m) {
            int rbase = row0 + wrow + m * 16 + lq * 4;
            int b = rbase >> 11, s = rbase & 2047;
            #pragma unroll
            for (int n = 0; n < 4; ++n) {
                int c = col0 + wcol + n * 16 + lm - 2048;
                u16x4 pk = { f2bf(acc[m][n][0] + bz[n]), f2bf(acc[m][n][1] + bz[n]),
                             f2bf(acc[m][n][2] + bz[n]), f2bf(acc[m][n][3] + bz[n]) };
                *(u16x4*)&Vt[(size_t)((b * 16 + (c >> 6)) * 64 + (c & 63)) * 2048 + s] = pk;
            }
        }
        return;
    }

    u16* Cz = (u16*)Cout + (EPI == 3 ? (size_t)blockIdx.z * M * N : 0);
    #pragma unroll
    for (int m = 0; m < 4; ++m) {
        #pragma unroll
        for (int e = 0; e < 4; ++e) {
            int row = row0 + wrow + m * 16 + lq * 4 + e;
            #pragma unroll
            for (int n = 0; n < 4; ++n) {
                int col = col0 + wcol + n * 16 + lm;
                float v = acc[m][n][e] + bz[n];
                if (EPI == 1) v = v > 0.f ? v : NEG_SLOPE * v;
                Cz[(size_t)row * N + col] = f2bf(v);
            }
        }
    }
}

// ---------------------------------------------------------------------------
// Flash attention, bf16 MFMA. LDS-staged K/V (coalesced) with one-iteration
// VGPR prefetch; no-max exp2 softmax (scale folded into Q weights); row sums
// via ones-MFMA; cheap trunc-round P conversion (numerator/denominator use
// the same quantized P, so rounding error cancels in the normalization).
// ---------------------------------------------------------------------------
__global__ __launch_bounds__(256)
void attn_mfma(const u16* __restrict__ QKV, const u16* __restrict__ Vt,
               u16* __restrict__ ctx)
{
    __shared__ u16 Qs[64 * 72];
    __shared__ u16 Ks[64 * 72];
    __shared__ u16 Vs[64 * 72];
    __shared__ u16 Ps[64 * 72];
    const int tid = threadIdx.x, w = tid >> 6, lane = tid & 63;
    const int lm = lane & 15, lq = lane >> 4;
    const int q0 = blockIdx.x * 64;
    const int bh = blockIdx.y;
    const int b  = bh >> 4, h = bh & 15;
    const size_t row_b = (size_t)b * SS;
    const int ccol = h * DKH;

    const int sr = tid >> 3;          // 0..31
    const int sc = (tid & 7) * 8;     // 0..56

    #pragma unroll
    for (int i = 0; i < 2; ++i) {
        int r = i * 32 + sr;
        *(bf16x8*)&Qs[r * 72 + sc] =
            *(const bf16x8*)(QKV + (row_b + q0 + r) * 3072 + ccol + sc);
    }
    bf16x8 kr[2], vr[2];
    #pragma unroll
    for (int i = 0; i < 2; ++i) {
        int r = i * 32 + sr;
        kr[i] = *(const bf16x8*)(QKV + (row_b + r) * 3072 + 1024 + ccol + sc);
        vr[i] = *(const bf16x8*)(Vt + ((size_t)bh * 64 + r) * SS + sc);
    }
    __syncthreads();
    bf16x8 aq0 = *(const bf16x8*)&Qs[(w * 16 + lm) * 72 + lq * 8];
    bf16x8 aq1 = *(const bf16x8*)&Qs[(w * 16 + lm) * 72 + 32 + lq * 8];

    bf16x8 ones;
    #pragma unroll
    for (int j = 0; j < 8; ++j) ones[j] = (__bf16)1.0f;

    f32x4 o[4] = {};
    f32x4 lacc = {};

    for (int kt = 0; kt < SS / 64; ++kt) {
        __syncthreads();   // A: done reading Ks/Vs (prev iter)
        #pragma unroll
        for (int i = 0; i < 2; ++i) {
            int r = i * 32 + sr;
            *(bf16x8*)&Ks[r * 72 + sc] = kr[i];
            *(bf16x8*)&Vs[r * 72 + sc] = vr[i];
        }
        const int kn = ((kt + 1) & 31) * 64;
        #pragma unroll
        for (int i = 0; i < 2; ++i) {
            int r = i * 32 + sr;
            kr[i] = *(const bf16x8*)(QKV + (row_b + kn + r) * 3072 + 1024 + ccol + sc);
            vr[i] = *(const bf16x8*)(Vt + ((size_t)bh * 64 + r) * SS + kn + sc);
        }
        __syncthreads();   // B: Ks/Vs visible

        f32x4 s[4] = {};
        #pragma unroll
        for (int n = 0; n < 4; ++n) {
            bf16x8 bk0 = *(const bf16x8*)&Ks[(n * 16 + lm) * 72 + lq * 8];
            bf16x8 bk1 = *(const bf16x8*)&Ks[(n * 16 + lm) * 72 + 32 + lq * 8];
            s[n] = __builtin_amdgcn_mfma_f32_16x16x32_bf16(aq0, bk0, s[n], 0, 0, 0);
            s[n] = __builtin_amdgcn_mfma_f32_16x16x32_bf16(aq1, bk1, s[n], 0, 0, 0);
        }
        const int prow = (w * 16 + lq * 4) * 72 + lm;
        #pragma unroll
        for (int n = 0; n < 4; ++n)
            #pragma unroll
            for (int e = 0; e < 4; ++e) {
                float p = __builtin_exp2f(s[n][e]);
                Ps[prow + e * 72 + n * 16] =
                    (u16)((__float_as_uint(p) + 0x8000u) >> 16);
            }
        __syncthreads();   // C: Ps visible

        bf16x8 ap0 = *(const bf16x8*)&Ps[(w * 16 + lm) * 72 + lq * 8];
        bf16x8 ap1 = *(const bf16x8*)&Ps[(w * 16 + lm) * 72 + 32 + lq * 8];
        #pragma unroll
        for (int n = 0; n < 4; ++n) {
            bf16x8 bv0 = *(const bf16x8*)&Vs[(n * 16 + lm) * 72 + lq * 8];
            bf16x8 bv1 = *(const bf16x8*)&Vs[(n * 16 + lm) * 72 + 32 + lq * 8];
            o[n] = __builtin_amdgcn_mfma_f32_16x16x32_bf16(ap0, bv0, o[n], 0, 0, 0);
            o[n] = __builtin_amdgcn_mfma_f32_16x16x32_bf16(ap1, bv1, o[n], 0, 0, 0);
        }
        lacc = __builtin_amdgcn_mfma_f32_16x16x32_bf16(ap0, ones, lacc, 0, 0, 0);
        lacc = __builtin_amdgcn_mfma_f32_16x16x32_bf16(ap1, ones, lacc, 0, 0, 0);
    }

    #pragma unroll
    for (int e = 0; e < 4; ++e) {
        float inv = 1.0f / lacc[e];
        int row = q0 + w * 16 + lq * 4 + e;
        u16* dst = ctx + (row_b + row) * D_MODEL + ccol;
        #pragma unroll
        for (int n = 0; n < 4; ++n)
            dst[n * 16 + lm] = f2bf(o[n][e] * inv);
    }
}

// ---------------------------------------------------------------------------
// out = LayerNorm(bf16 C0 + bf16 C1 + cbias + resid) * g + beta.
// OUTF32: 1 -> float4 out; 0 -> bf16 out. RESBF: residual bf16 vs f32.
// ---------------------------------------------------------------------------
template<int OUTF32, int RESBF>
__global__ __launch_bounds__(256)
void add_ln(const u16* __restrict__ C0, const u16* __restrict__ C1,
            const float* __restrict__ cbias, const void* __restrict__ resid,
            const float* __restrict__ g, const float* __restrict__ beta,
            float* __restrict__ outf, u16* __restrict__ outb)
{
    __shared__ float red[8];
    const int row = blockIdx.x;
    const int tid = threadIdx.x;
    u16x4 p0 = ((const u16x4*)(C0 + (size_t)row * D_MODEL))[tid];
    u16x4 p1 = ((const u16x4*)(C1 + (size_t)row * D_MODEL))[tid];
    float4 cb = ((const float4*)cbias)[tid];
    float4 rr;
    if (RESBF) {
        u16x4 rb = ((const u16x4*)((const u16*)resid + (size_t)row * D_MODEL))[tid];
        rr = { bf2f(rb.x), bf2f(rb.y), bf2f(rb.z), bf2f(rb.w) };
    } else {
        rr = ((const float4*)((const float*)resid + (size_t)row * D_MODEL))[tid];
    }
    float4 v = { bf2f(p0.x) + bf2f(p1.x) + cb.x + rr.x,
                 bf2f(p0.y) + bf2f(p1.y) + cb.y + rr.y,
                 bf2f(p0.z) + bf2f(p1.z) + cb.z + rr.z,
                 bf2f(p0.w) + bf2f(p1.w) + cb.w + rr.w };
    float s  = v.x + v.y + v.z + v.w;
    float sq = v.x*v.x + v.y*v.y + v.z*v.z + v.w*v.w;
    #pragma unroll
    for (int off = 32; off > 0; off >>= 1) {
        s  += __shfl_down(s,  off, 64);
        sq += __shfl_down(sq, off, 64);
    }
    const int wv = tid >> 6;
    if ((tid & 63) == 0) { red[wv] = s; red[4 + wv] = sq; }
    __syncthreads();
    float st  = red[0] + red[1] + red[2] + red[3];
    float sqt = red[4] + red[5] + red[6] + red[7];
    float mu   = st * (1.0f / D_MODEL);
    float var  = sqt * (1.0f / D_MODEL) - mu * mu;
    float rstd = rsqrtf(var + EPSLN);
    float4 gv = ((const float4*)g)[tid];
    float4 bt = ((const float4*)beta)[tid];
    float4 ov;
    ov.x = (v.x - mu) * rstd * gv.x + bt.x;
    ov.y = (v.y - mu) * rstd * gv.y + bt.y;
    ov.z = (v.z - mu) * rstd * gv.z + bt.z;
    ov.w = (v.w - mu) * rstd * gv.w + bt.w;
    if (OUTF32) {
        ((float4*)(outf + (size_t)row * D_MODEL))[tid] = ov;
    } else {
        u16x4 ob = { f2bf(ov.x), f2bf(ov.y), f2bf(ov.z), f2bf(ov.w) };
        ((u16x4*)(outb + (size_t)row * D_MODEL))[tid] = ob;
    }
}

// ---------------------------------------------------------------------------
extern "C" void kernel_launch(void* const* d_in, const int* in_sizes, int n_in,
                              void* d_out, int out_size, void* d_ws, size_t ws_size,
                              hipStream_t stream) {
    const float* x     = (const float*)d_in[0];
    const float* wq    = (const float*)d_in[1];
    const float* bq    = (const float*)d_in[2];
    const float* wk    = (const float*)d_in[3];
    const float* bk    = (const float*)d_in[4];
    const float* wv    = (const float*)d_in[5];
    const float* bv    = (const float*)d_in[6];
    const float* wo    = (const float*)d_in[7];
    const float* bo    = (const float*)d_in[8];
    const float* g1    = (const float*)d_in[9];
    const float* b1    = (const float*)d_in[10];
    const float* w_ff1 = (const float*)d_in[11];
    const float* b_ff1 = (const float*)d_in[12];
    const float* w_ff2 = (const float*)d_in[13];
    const float* b_ff2 = (const float*)d_in[14];
    const float* g2    = (const float*)d_in[15];
    const float* b2    = (const float*)d_in[16];
    float* out = (float*)d_out;

    const float qscale = 0.18033688011112042f;   // log2(e) / sqrt(DK)

    char* W = (char*)d_ws;
    u16*   x_bf    = (u16*)(W + 0);             // 8.4 MB (later: ctx)
    u16*   wqkvT   = (u16*)(W + 8388608);       // 6.3 MB
    u16*   woT     = (u16*)(W + 14680064);      // 2.1 MB
    u16*   wff1T   = (u16*)(W + 16777216);      // 8.4 MB
    u16*   wff2T   = (u16*)(W + 25165824);      // 8.4 MB
    u16*   QKV     = (u16*)(W + 33554432);      // 25.2 MB (later: ff1 spans QKV+VtG)
    u16*   VtG     = (u16*)(W + 58720256);      // 8.4 MB
    u16*   C0      = (u16*)(W + 67108864);      // 8.4 MB (split-K partial 0, bf16)
    u16*   C1      = (u16*)(W + 75497472);      // 8.4 MB (split-K partial 1, bf16)
    u16*   h_bf    = (u16*)(W + 83886080);      // 8.4 MB
    float* qkv_bias= (float*)(W + 92274688);    // 12 KB
    u16*   ctx     = x_bf;
    u16*   ff1_bf  = QKV;

    dim3 blk(256);
    // --- fused prep: x->bf16, all weight transposes, bias concat ---
    prep<<<7180, blk, 0, stream>>>(x, x_bf, wq, wk, wv, wo, w_ff1, w_ff2,
                                   wqkvT, woT, wff1T, wff2T,
                                   bq, bk, bv, qkv_bias, qscale);
    // --- QKV projection; V written transposed straight into VtG ---
    gemm_bf16<4><<<dim3(24, 32, 1), blk, 0, stream>>>(x_bf, wqkvT, qkv_bias, QKV, VtG, MTOT, 3072, 1024, 1024);
    // --- attention ---
    attn_mfma<<<dim3(32, 32), blk, 0, stream>>>(QKV, VtG, ctx);
    // --- output projection, split-K=2 (bf16 partials; bias folded into LN1) ---
    gemm_bf16<3><<<dim3(8, 32, 2), blk, 0, stream>>>(ctx, woT, nullptr, C0, nullptr, MTOT, 1024, 512, 1024);
    // --- residual + LN1 -> bf16 h ---
    add_ln<0, 0><<<MTOT, blk, 0, stream>>>(C0, C1, bo, x, g1, b1, nullptr, h_bf);
    // --- FFN ---
    gemm_bf16<1><<<dim3(32, 32, 1), blk, 0, stream>>>(h_bf, wff1T, b_ff1, ff1_bf, nullptr, MTOT, DFF_, 1024, 1024);
    gemm_bf16<3><<<dim3(8, 32, 2), blk, 0, stream>>>(ff1_bf, wff2T, nullptr, C0, nullptr, MTOT, 1024, 2048, 4096);
    // --- residual + LN2 -> f32 out ---
    add_ln<1, 1><<<MTOT, blk, 0, stream>>>(C0, C1, b_ff2, h_bf, g2, b2, out, nullptr);
}

// Round 6
// 382.117 us; speedup vs baseline: 1.6366x; 1.0115x over previous
//
#include <hip/hip_runtime.h>
#include <math.h>

#define D_MODEL 1024
#define NHEAD   16
#define DKH     64
#define DFF_    4096
#define BB      2
#define SS      2048
#define MTOT    (BB*SS)
#define EPSLN   1e-6f
#define NEG_SLOPE 0.01f

typedef unsigned short u16;
typedef unsigned int   u32;
typedef __bf16 bf16x8 __attribute__((ext_vector_type(8)));
typedef float  f32x4  __attribute__((ext_vector_type(4)));
typedef u16    u16x4  __attribute__((ext_vector_type(4)));

__device__ __forceinline__ u16 f2bf(float f) {
    u32 u = __float_as_uint(f);
    u = (u + 0x7fffu + ((u >> 16) & 1u)) >> 16;
    return (u16)u;
}
__device__ __forceinline__ float bf2f(u16 u) {
    return __uint_as_float(((u32)u) << 16);
}

__device__ __forceinline__ void gload_lds16(const u16* g, u16* l) {
    __builtin_amdgcn_global_load_lds(
        (const __attribute__((address_space(1))) u32*)g,
        (__attribute__((address_space(3))) u32*)l,
        16, 0, 0);
}

// ---------------------------------------------------------------------------
// 64x64 fp32->bf16 transpose tile (device helper for prep kernel)
// ---------------------------------------------------------------------------
__device__ __forceinline__ void transpose_tile(const float* __restrict__ W,
        u16* __restrict__ WT, int N, int out_stride, int out_row_off,
        float scale, int bx, int by, u16* T)
{
    const int t  = threadIdx.x;
    const int n0 = bx * 64;
    const int k0 = by * 64;
    #pragma unroll
    for (int i = 0; i < 4; ++i) {
        int r = i * 16 + (t >> 4);          // k
        int c = (t & 15) * 4;               // n
        float4 v = *(const float4*)&W[(size_t)(k0 + r) * N + n0 + c];
        T[(c + 0) * 72 + r] = f2bf(v.x * scale);
        T[(c + 1) * 72 + r] = f2bf(v.y * scale);
        T[(c + 2) * 72 + r] = f2bf(v.z * scale);
        T[(c + 3) * 72 + r] = f2bf(v.w * scale);
    }
    __syncthreads();
    #pragma unroll
    for (int i = 0; i < 4; ++i) {
        int nr = i * 16 + (t >> 4);
        int kc = (t & 15) * 4;
        u16x4 o = { T[nr*72 + kc], T[nr*72 + kc + 1], T[nr*72 + kc + 2], T[nr*72 + kc + 3] };
        *(u16x4*)&WT[(size_t)(out_row_off + n0 + nr) * out_stride + k0 + kc] = o;
    }
}

// ---------------------------------------------------------------------------
// Fused prep: x f32->bf16 | 4 square W transposes | ff1 | ff2 | bias concat.
// ---------------------------------------------------------------------------
__global__ __launch_bounds__(256)
void prep(const float* __restrict__ x, u16* __restrict__ x_bf,
          const float* __restrict__ wq, const float* __restrict__ wk,
          const float* __restrict__ wv, const float* __restrict__ wo,
          const float* __restrict__ wff1, const float* __restrict__ wff2,
          u16* __restrict__ wqkvT, u16* __restrict__ woT,
          u16* __restrict__ wff1T, u16* __restrict__ wff2T,
          const float* __restrict__ bq, const float* __restrict__ bk,
          const float* __restrict__ bv, float* __restrict__ qkv_bias,
          float qscale)
{
    __shared__ u16 T[64 * 72];
    int blk = blockIdx.x;
    if (blk < 4096) {
        int i = blk * 256 + threadIdx.x;
        float4 v = ((const float4*)x)[i];
        u16x4 o = { f2bf(v.x), f2bf(v.y), f2bf(v.z), f2bf(v.w) };
        ((u16x4*)x_bf)[i] = o;
        return;
    }
    blk -= 4096;
    if (blk < 1024) {   // wq/wk/wv/wo
        int which = blk >> 8, r = blk & 255;
        const float* Ws = which == 0 ? wq : which == 1 ? wk : which == 2 ? wv : wo;
        u16* Wd   = which == 3 ? woT : wqkvT;
        int off   = which == 3 ? 0 : which * 1024;
        float sc  = which == 0 ? qscale : 1.0f;
        transpose_tile(Ws, Wd, 1024, 1024, off, sc, r & 15, r >> 4, T);
        return;
    }
    blk -= 1024;
    if (blk < 1024) {
        transpose_tile(wff1, wff1T, 4096, 1024, 0, 1.0f, blk & 63, blk >> 6, T);
        return;
    }
    blk -= 1024;
    if (blk < 1024) {
        transpose_tile(wff2, wff2T, 1024, 4096, 0, 1.0f, blk & 15, blk >> 4, T);
        return;
    }
    blk -= 1024;
    int i = blk * 256 + threadIdx.x;
    qkv_bias[i] = (i < 1024) ? bq[i] * qscale
                : (i < 2048) ? bk[i - 1024] : bv[i - 2048];
}

// ---------------------------------------------------------------------------
// bf16 MFMA GEMM: C[M,N] = A[M, k_off:+k_len] @ BT[N,...]^T (+ bias).
// 128x128 tile, BK=64 (32 MFMA per barrier pair), global_load_lds staging
// with XOR chunk swizzle (rows of 8x16B chunks; chunk c holds src chunk
// c^(row&7); 2-way banks max on ds_read_b128).
// EPI: 1 = bf16 + bias + LeakyReLU
//      3 = bf16 partials (no bias) at Cout + z*M*N
//      4 = QKV special: cols <2048 bf16+bias into QKV; cols >=2048 (V)
//          written transposed into Vt[bh*64+d][SS]
// ---------------------------------------------------------------------------
template<int EPI>
__global__ __launch_bounds__(256)
void gemm_bf16(const u16* __restrict__ A, const u16* __restrict__ BT,
               const float* __restrict__ bias, void* __restrict__ Cout,
               u16* __restrict__ Vt, int M, int N, int k_len, int kstride)
{
    __shared__ u16 As[128 * 64];
    __shared__ u16 Bs[128 * 64];
    const int tid  = threadIdx.x;
    const int w    = tid >> 6;
    const int lane = tid & 63;
    const int lm   = lane & 15;
    const int lq   = lane >> 4;
    const int row0 = blockIdx.y * 128;
    const int col0 = blockIdx.x * 128;
    const int k_off = blockIdx.z * k_len;
    const int wrow = (w >> 1) * 64;
    const int wcol = (w & 1) * 64;

    f32x4 acc[4][4] = {};

    // staging: wave w covers rows w*32..+31 (4 issues of 8 rows each)
    const int r_i = lane >> 3;                 // 0..7 row in 8-group
    const int csw = ((lane & 7) ^ r_i) * 8;    // swizzled src chunk offset
    const u16* a_src = A  + (size_t)(row0 + w * 32 + r_i) * kstride + k_off + csw;
    const u16* b_src = BT + (size_t)(col0 + w * 32 + r_i) * kstride + k_off + csw;
    u16* a_dst = &As[(w * 32) * 64];
    u16* b_dst = &Bs[(w * 32) * 64];

    // fragment read offsets: chunk (h*4+lq) ^ (lm&7)
    const int fr0 = (lq ^ (lm & 7)) * 8;
    const int fr1 = ((4 + lq) ^ (lm & 7)) * 8;
    const u16* a_rd = &As[(wrow + lm) * 64];
    const u16* b_rd = &Bs[(wcol + lm) * 64];

    for (int k0 = 0; k0 < k_len; k0 += 64) {
        #pragma unroll
        for (int i = 0; i < 4; ++i) {
            gload_lds16(a_src + k0 + (size_t)(i * 8) * kstride, a_dst + (i * 8) * 64);
            gload_lds16(b_src + k0 + (size_t)(i * 8) * kstride, b_dst + (i * 8) * 64);
        }
        __syncthreads();
        #pragma unroll
        for (int h = 0; h < 2; ++h) {
            const int fo = h ? fr1 : fr0;
            bf16x8 av[4], bv[4];
            #pragma unroll
            for (int m = 0; m < 4; ++m) av[m] = *(const bf16x8*)(a_rd + m * 16 * 64 + fo);
            #pragma unroll
            for (int n = 0; n < 4; ++n) bv[n] = *(const bf16x8*)(b_rd + n * 16 * 64 + fo);
            #pragma unroll
            for (int m = 0; m < 4; ++m)
                #pragma unroll
                for (int n = 0; n < 4; ++n)
                    acc[m][n] = __builtin_amdgcn_mfma_f32_16x16x32_bf16(av[m], bv[n], acc[m][n], 0, 0, 0);
        }
        __syncthreads();
    }

    float bz[4] = {0.f, 0.f, 0.f, 0.f};
    if (EPI != 3) {
        #pragma unroll
        for (int n = 0; n < 4; ++n) bz[n] = bias[col0 + wcol + n * 16 + lm];
    }

    if (EPI == 4 && col0 >= 2048) {
        // V part -> Vt[(b*16+h)*64 + d][2048]
        #pragma unroll
        for (int m = 0; m < 4; ++m) {
            int rbase = row0 + wrow + m * 16 + lq * 4;
            int b = rbase >> 11, s = rbase & 2047;
            #pragma unroll
            for (int n = 0; n < 4; ++n) {
                int c = col0 + wcol + n * 16 + lm - 2048;
                u16x4 pk = { f2bf(acc[m][n][0] + bz[n]), f2bf(acc[m][n][1] + bz[n]),
                             f2bf(acc[m][n][2] + bz[n]), f2bf(acc[m][n][3] + bz[n]) };
                *(u16x4*)&Vt[(size_t)((b * 16 + (c >> 6)) * 64 + (c & 63)) * 2048 + s] = pk;
            }
        }
        return;
    }

    u16* Cz = (u16*)Cout + (EPI == 3 ? (size_t)blockIdx.z * M * N : 0);
    #pragma unroll
    for (int m = 0; m < 4; ++m) {
        #pragma unroll
        for (int e = 0; e < 4; ++e) {
            int row = row0 + wrow + m * 16 + lq * 4 + e;
            #pragma unroll
            for (int n = 0; n < 4; ++n) {
                int col = col0 + wcol + n * 16 + lm;
                float v = acc[m][n][e] + bz[n];
                if (EPI == 1) v = v > 0.f ? v : NEG_SLOPE * v;
                Cz[(size_t)row * N + col] = f2bf(v);
            }
        }
    }
}

// ---------------------------------------------------------------------------
// Flash attention, bf16 MFMA. K/V staged via global_load_lds (XOR chunk
// swizzle) into double-buffered LDS, DMA for tile kt+1 issued at top of
// iter kt -> one barrier per key-tile. P and Q are wave-private (wave w
// writes AND reads rows w*16..+15) so the P round-trip needs no barrier.
// No-max exp2 softmax (scale folded into Q weights); row sums via ones-MFMA.
// ---------------------------------------------------------------------------
__global__ __launch_bounds__(256)
void attn_mfma(const u16* __restrict__ QKV, const u16* __restrict__ Vt,
               u16* __restrict__ ctx)
{
    __shared__ u16 QP[64 * 72];       // Q staged unpadded [r*64+c]; later P [r*72+c]
    __shared__ u16 Kb[2][64 * 64];
    __shared__ u16 Vb[2][64 * 64];
    const int tid = threadIdx.x, w = tid >> 6, lane = tid & 63;
    const int lm = lane & 15, lq = lane >> 4;
    const int q0 = blockIdx.x * 64;
    const int bh = blockIdx.y;
    const int b  = bh >> 4, h = bh & 15;
    const size_t row_b = (size_t)b * SS;
    const int ccol = h * DKH;

    // staging geometry: wave w stages rows w*16..+15 (2 issues of 8 rows)
    const int r_i = lane >> 3;                 // 0..7
    const int csw = ((lane & 7) ^ r_i) * 8;    // swizzled chunk offset
    const u16* ksrc = QKV + (row_b + w * 16 + r_i) * 3072 + 1024 + ccol + csw;
    const u16* vsrc = Vt + ((size_t)bh * 64 + w * 16 + r_i) * SS + csw;
    const u16* qsrc = QKV + (row_b + q0 + w * 16 + r_i) * 3072 + ccol + csw;

    gload_lds16(qsrc,                    &QP[(w * 16) * 64]);
    gload_lds16(qsrc + (size_t)8 * 3072, &QP[(w * 16 + 8) * 64]);
    #pragma unroll
    for (int i = 0; i < 2; ++i) {
        gload_lds16(ksrc + (size_t)(i * 8) * 3072, &Kb[0][(w * 16 + i * 8) * 64]);
        gload_lds16(vsrc + (size_t)(i * 8) * SS,   &Vb[0][(w * 16 + i * 8) * 64]);
    }
    __syncthreads();   // drain DMA: Q/K0/V0 visible

    const int fr0 = (lq ^ (lm & 7)) * 8;
    const int fr1 = ((4 + lq) ^ (lm & 7)) * 8;
    bf16x8 aq0 = *(const bf16x8*)&QP[(w * 16 + lm) * 64 + fr0];
    bf16x8 aq1 = *(const bf16x8*)&QP[(w * 16 + lm) * 64 + fr1];
    __syncthreads();   // all waves hold Q in regs before P overwrites QP

    bf16x8 ones;
    #pragma unroll
    for (int j = 0; j < 8; ++j) ones[j] = (__bf16)1.0f;

    f32x4 o[4] = {};
    f32x4 lacc = {};

    for (int kt = 0; kt < SS / 64; ++kt) {
        const int cur = kt & 1;
        if (kt < SS / 64 - 1) {
            const int nxt = cur ^ 1;
            const size_t koff = (size_t)(kt + 1) * 64;
            #pragma unroll
            for (int i = 0; i < 2; ++i) {
                gload_lds16(ksrc + (koff + i * 8) * 3072, &Kb[nxt][(w * 16 + i * 8) * 64]);
                gload_lds16(vsrc + koff + (size_t)(i * 8) * SS, &Vb[nxt][(w * 16 + i * 8) * 64]);
            }
        }
        f32x4 s[4] = {};
        #pragma unroll
        for (int n = 0; n < 4; ++n) {
            bf16x8 bk0 = *(const bf16x8*)&Kb[cur][(n * 16 + lm) * 64 + fr0];
            bf16x8 bk1 = *(const bf16x8*)&Kb[cur][(n * 16 + lm) * 64 + fr1];
            s[n] = __builtin_amdgcn_mfma_f32_16x16x32_bf16(aq0, bk0, s[n], 0, 0, 0);
            s[n] = __builtin_amdgcn_mfma_f32_16x16x32_bf16(aq1, bk1, s[n], 0, 0, 0);
        }
        // P = 2^S, wave-private rows -> no barrier around the LDS round-trip
        const int prow = (w * 16 + lq * 4) * 72 + lm;
        #pragma unroll
        for (int n = 0; n < 4; ++n)
            #pragma unroll
            for (int e = 0; e < 4; ++e) {
                float p = __builtin_exp2f(s[n][e]);
                QP[prow + e * 72 + n * 16] =
                    (u16)((__float_as_uint(p) + 0x8000u) >> 16);
            }
        bf16x8 ap0 = *(const bf16x8*)&QP[(w * 16 + lm) * 72 + lq * 8];
        bf16x8 ap1 = *(const bf16x8*)&QP[(w * 16 + lm) * 72 + 32 + lq * 8];
        #pragma unroll
        for (int n = 0; n < 4; ++n) {
            bf16x8 bv0 = *(const bf16x8*)&Vb[cur][(n * 16 + lm) * 64 + fr0];
            bf16x8 bv1 = *(const bf16x8*)&Vb[cur][(n * 16 + lm) * 64 + fr1];
            o[n] = __builtin_amdgcn_mfma_f32_16x16x32_bf16(ap0, bv0, o[n], 0, 0, 0);
            o[n] = __builtin_amdgcn_mfma_f32_16x16x32_bf16(ap1, bv1, o[n], 0, 0, 0);
        }
        lacc = __builtin_amdgcn_mfma_f32_16x16x32_bf16(ap0, ones, lacc, 0, 0, 0);
        lacc = __builtin_amdgcn_mfma_f32_16x16x32_bf16(ap1, ones, lacc, 0, 0, 0);
        __syncthreads();   // all waves done with cur; nxt DMA drained
    }

    #pragma unroll
    for (int e = 0; e < 4; ++e) {
        float inv = 1.0f / lacc[e];
        int row = q0 + w * 16 + lq * 4 + e;
        u16* dst = ctx + (row_b + row) * D_MODEL + ccol;
        #pragma unroll
        for (int n = 0; n < 4; ++n)
            dst[n * 16 + lm] = f2bf(o[n][e] * inv);
    }
}

// ---------------------------------------------------------------------------
// out = LayerNorm(bf16 C0 + bf16 C1 + cbias + resid) * g + beta.
// ---------------------------------------------------------------------------
template<int OUTF32, int RESBF>
__global__ __launch_bounds__(256)
void add_ln(const u16* __restrict__ C0, const u16* __restrict__ C1,
            const float* __restrict__ cbias, const void* __restrict__ resid,
            const float* __restrict__ g, const float* __restrict__ beta,
            float* __restrict__ outf, u16* __restrict__ outb)
{
    __shared__ float red[8];
    const int row = blockIdx.x;
    const int tid = threadIdx.x;
    u16x4 p0 = ((const u16x4*)(C0 + (size_t)row * D_MODEL))[tid];
    u16x4 p1 = ((const u16x4*)(C1 + (size_t)row * D_MODEL))[tid];
    float4 cb = ((const float4*)cbias)[tid];
    float4 rr;
    if (RESBF) {
        u16x4 rb = ((const u16x4*)((const u16*)resid + (size_t)row * D_MODEL))[tid];
        rr = { bf2f(rb.x), bf2f(rb.y), bf2f(rb.z), bf2f(rb.w) };
    } else {
        rr = ((const float4*)((const float*)resid + (size_t)row * D_MODEL))[tid];
    }
    float4 v = { bf2f(p0.x) + bf2f(p1.x) + cb.x + rr.x,
                 bf2f(p0.y) + bf2f(p1.y) + cb.y + rr.y,
                 bf2f(p0.z) + bf2f(p1.z) + cb.z + rr.z,
                 bf2f(p0.w) + bf2f(p1.w) + cb.w + rr.w };
    float s  = v.x + v.y + v.z + v.w;
    float sq = v.x*v.x + v.y*v.y + v.z*v.z + v.w*v.w;
    #pragma unroll
    for (int off = 32; off > 0; off >>= 1) {
        s  += __shfl_down(s,  off, 64);
        sq += __shfl_down(sq, off, 64);
    }
    const int wv = tid >> 6;
    if ((tid & 63) == 0) { red[wv] = s; red[4 + wv] = sq; }
    __syncthreads();
    float st  = red[0] + red[1] + red[2] + red[3];
    float sqt = red[4] + red[5] + red[6] + red[7];
    float mu   = st * (1.0f / D_MODEL);
    float var  = sqt * (1.0f / D_MODEL) - mu * mu;
    float rstd = rsqrtf(var + EPSLN);
    float4 gv = ((const float4*)g)[tid];
    float4 bt = ((const float4*)beta)[tid];
    float4 ov;
    ov.x = (v.x - mu) * rstd * gv.x + bt.x;
    ov.y = (v.y - mu) * rstd * gv.y + bt.y;
    ov.z = (v.z - mu) * rstd * gv.z + bt.z;
    ov.w = (v.w - mu) * rstd * gv.w + bt.w;
    if (OUTF32) {
        ((float4*)(outf + (size_t)row * D_MODEL))[tid] = ov;
    } else {
        u16x4 ob = { f2bf(ov.x), f2bf(ov.y), f2bf(ov.z), f2bf(ov.w) };
        ((u16x4*)(outb + (size_t)row * D_MODEL))[tid] = ob;
    }
}

// ---------------------------------------------------------------------------
extern "C" void kernel_launch(void* const* d_in, const int* in_sizes, int n_in,
                              void* d_out, int out_size, void* d_ws, size_t ws_size,
                              hipStream_t stream) {
    const float* x     = (const float*)d_in[0];
    const float* wq    = (const float*)d_in[1];
    const float* bq    = (const float*)d_in[2];
    const float* wk    = (const float*)d_in[3];
    const float* bk    = (const float*)d_in[4];
    const float* wv    = (const float*)d_in[5];
    const float* bv    = (const float*)d_in[6];
    const float* wo    = (const float*)d_in[7];
    const float* bo    = (const float*)d_in[8];
    const float* g1    = (const float*)d_in[9];
    const float* b1    = (const float*)d_in[10];
    const float* w_ff1 = (const float*)d_in[11];
    const float* b_ff1 = (const float*)d_in[12];
    const float* w_ff2 = (const float*)d_in[13];
    const float* b_ff2 = (const float*)d_in[14];
    const float* g2    = (const float*)d_in[15];
    const float* b2    = (const float*)d_in[16];
    float* out = (float*)d_out;

    const float qscale = 0.18033688011112042f;   // log2(e) / sqrt(DK)

    char* W = (char*)d_ws;
    u16*   x_bf    = (u16*)(W + 0);             // 8.4 MB (later: ctx)
    u16*   wqkvT   = (u16*)(W + 8388608);       // 6.3 MB
    u16*   woT     = (u16*)(W + 14680064);      // 2.1 MB
    u16*   wff1T   = (u16*)(W + 16777216);      // 8.4 MB
    u16*   wff2T   = (u16*)(W + 25165824);      // 8.4 MB
    u16*   QKV     = (u16*)(W + 33554432);      // 25.2 MB (later: ff1)
    u16*   VtG     = (u16*)(W + 58720256);      // 8.4 MB
    u16*   C0      = (u16*)(W + 67108864);      // 8.4 MB (split-K partial 0)
    u16*   C1      = (u16*)(W + 75497472);      // 8.4 MB (split-K partial 1)
    u16*   h_bf    = (u16*)(W + 83886080);      // 8.4 MB
    float* qkv_bias= (float*)(W + 92274688);    // 12 KB
    u16*   ctx     = x_bf;
    u16*   ff1_bf  = QKV;

    dim3 blk(256);
    prep<<<7180, blk, 0, stream>>>(x, x_bf, wq, wk, wv, wo, w_ff1, w_ff2,
                                   wqkvT, woT, wff1T, wff2T,
                                   bq, bk, bv, qkv_bias, qscale);
    gemm_bf16<4><<<dim3(24, 32, 1), blk, 0, stream>>>(x_bf, wqkvT, qkv_bias, QKV, VtG, MTOT, 3072, 1024, 1024);
    attn_mfma<<<dim3(32, 32), blk, 0, stream>>>(QKV, VtG, ctx);
    gemm_bf16<3><<<dim3(8, 32, 2), blk, 0, stream>>>(ctx, woT, nullptr, C0, nullptr, MTOT, 1024, 512, 1024);
    add_ln<0, 0><<<MTOT, blk, 0, stream>>>(C0, C1, bo, x, g1, b1, nullptr, h_bf);
    gemm_bf16<1><<<dim3(32, 32, 1), blk, 0, stream>>>(h_bf, wff1T, b_ff1, ff1_bf, nullptr, MTOT, DFF_, 1024, 1024);
    gemm_bf16<3><<<dim3(8, 32, 2), blk, 0, stream>>>(ff1_bf, wff2T, nullptr, C0, nullptr, MTOT, 1024, 2048, 4096);
    add_ln<1, 1><<<MTOT, blk, 0, stream>>>(C0, C1, b_ff2, h_bf, g2, b2, out, nullptr);
}

// Round 7
// 359.278 us; speedup vs baseline: 1.7406x; 1.0636x over previous
//
#include <hip/hip_runtime.h>
#include <math.h>

#define D_MODEL 1024
#define NHEAD   16
#define DKH     64
#define DFF_    4096
#define BB      2
#define SS      2048
#define MTOT    (BB*SS)
#define EPSLN   1e-6f
#define NEG_SLOPE 0.01f

typedef unsigned short u16;
typedef unsigned int   u32;
typedef __bf16 bf16x8 __attribute__((ext_vector_type(8)));
typedef float  f32x4  __attribute__((ext_vector_type(4)));
typedef u16    u16x4  __attribute__((ext_vector_type(4)));

__device__ __forceinline__ u16 f2bf(float f) {
    u32 u = __float_as_uint(f);
    u = (u + 0x7fffu + ((u >> 16) & 1u)) >> 16;
    return (u16)u;
}
__device__ __forceinline__ float bf2f(u16 u) {
    return __uint_as_float(((u32)u) << 16);
}

__device__ __forceinline__ void gload_lds16(const u16* g, u16* l) {
    __builtin_amdgcn_global_load_lds(
        (const __attribute__((address_space(1))) u32*)g,
        (__attribute__((address_space(3))) u32*)l,
        16, 0, 0);
}

// ---------------------------------------------------------------------------
// 64x64 fp32->bf16 transpose tile (device helper for prep kernel)
// ---------------------------------------------------------------------------
__device__ __forceinline__ void transpose_tile(const float* __restrict__ W,
        u16* __restrict__ WT, int N, int out_stride, int out_row_off,
        float scale, int bx, int by, u16* T)
{
    const int t  = threadIdx.x;
    const int n0 = bx * 64;
    const int k0 = by * 64;
    #pragma unroll
    for (int i = 0; i < 4; ++i) {
        int r = i * 16 + (t >> 4);          // k
        int c = (t & 15) * 4;               // n
        float4 v = *(const float4*)&W[(size_t)(k0 + r) * N + n0 + c];
        T[(c + 0) * 72 + r] = f2bf(v.x * scale);
        T[(c + 1) * 72 + r] = f2bf(v.y * scale);
        T[(c + 2) * 72 + r] = f2bf(v.z * scale);
        T[(c + 3) * 72 + r] = f2bf(v.w * scale);
    }
    __syncthreads();
    #pragma unroll
    for (int i = 0; i < 4; ++i) {
        int nr = i * 16 + (t >> 4);
        int kc = (t & 15) * 4;
        u16x4 o = { T[nr*72 + kc], T[nr*72 + kc + 1], T[nr*72 + kc + 2], T[nr*72 + kc + 3] };
        *(u16x4*)&WT[(size_t)(out_row_off + n0 + nr) * out_stride + k0 + kc] = o;
    }
}

// ---------------------------------------------------------------------------
// Fused prep: x f32->bf16 | 4 square W transposes | ff1 | ff2 | bias concat.
// ---------------------------------------------------------------------------
__global__ __launch_bounds__(256)
void prep(const float* __restrict__ x, u16* __restrict__ x_bf,
          const float* __restrict__ wq, const float* __restrict__ wk,
          const float* __restrict__ wv, const float* __restrict__ wo,
          const float* __restrict__ wff1, const float* __restrict__ wff2,
          u16* __restrict__ wqkvT, u16* __restrict__ woT,
          u16* __restrict__ wff1T, u16* __restrict__ wff2T,
          const float* __restrict__ bq, const float* __restrict__ bk,
          const float* __restrict__ bv, float* __restrict__ qkv_bias,
          float qscale)
{
    __shared__ u16 T[64 * 72];
    int blk = blockIdx.x;
    if (blk < 4096) {
        int i = blk * 256 + threadIdx.x;
        float4 v = ((const float4*)x)[i];
        u16x4 o = { f2bf(v.x), f2bf(v.y), f2bf(v.z), f2bf(v.w) };
        ((u16x4*)x_bf)[i] = o;
        return;
    }
    blk -= 4096;
    if (blk < 1024) {   // wq/wk/wv/wo
        int which = blk >> 8, r = blk & 255;
        const float* Ws = which == 0 ? wq : which == 1 ? wk : which == 2 ? wv : wo;
        u16* Wd   = which == 3 ? woT : wqkvT;
        int off   = which == 3 ? 0 : which * 1024;
        float sc  = which == 0 ? qscale : 1.0f;
        transpose_tile(Ws, Wd, 1024, 1024, off, sc, r & 15, r >> 4, T);
        return;
    }
    blk -= 1024;
    if (blk < 1024) {
        transpose_tile(wff1, wff1T, 4096, 1024, 0, 1.0f, blk & 63, blk >> 6, T);
        return;
    }
    blk -= 1024;
    if (blk < 1024) {
        transpose_tile(wff2, wff2T, 1024, 4096, 0, 1.0f, blk & 15, blk >> 4, T);
        return;
    }
    blk -= 1024;
    int i = blk * 256 + threadIdx.x;
    qkv_bias[i] = (i < 1024) ? bq[i] * qscale
                : (i < 2048) ? bk[i - 1024] : bv[i - 2048];
}

// ---------------------------------------------------------------------------
// bf16 MFMA GEMM: C[M,N] = A[M, k_off:+k_len] @ BT[N,...]^T (+ bias).
// 128x128 tile, BK=64 (32 MFMA per barrier pair), global_load_lds staging
// with XOR chunk swizzle.
// EPI: 1 = bf16 + bias + LeakyReLU
//      3 = bf16 partials (no bias) at Cout + z*M*N
//      4 = QKV special: cols <2048 bf16+bias into QKV; cols >=2048 (V)
//          written transposed into Vt[bh*64+d][SS]
// ---------------------------------------------------------------------------
template<int EPI>
__global__ __launch_bounds__(256)
void gemm_bf16(const u16* __restrict__ A, const u16* __restrict__ BT,
               const float* __restrict__ bias, void* __restrict__ Cout,
               u16* __restrict__ Vt, int M, int N, int k_len, int kstride)
{
    __shared__ u16 As[128 * 64];
    __shared__ u16 Bs[128 * 64];
    const int tid  = threadIdx.x;
    const int w    = tid >> 6;
    const int lane = tid & 63;
    const int lm   = lane & 15;
    const int lq   = lane >> 4;
    const int row0 = blockIdx.y * 128;
    const int col0 = blockIdx.x * 128;
    const int k_off = blockIdx.z * k_len;
    const int wrow = (w >> 1) * 64;
    const int wcol = (w & 1) * 64;

    f32x4 acc[4][4] = {};

    const int r_i = lane >> 3;                 // 0..7 row in 8-group
    const int csw = ((lane & 7) ^ r_i) * 8;    // swizzled src chunk offset
    const u16* a_src = A  + (size_t)(row0 + w * 32 + r_i) * kstride + k_off + csw;
    const u16* b_src = BT + (size_t)(col0 + w * 32 + r_i) * kstride + k_off + csw;
    u16* a_dst = &As[(w * 32) * 64];
    u16* b_dst = &Bs[(w * 32) * 64];

    const int fr0 = (lq ^ (lm & 7)) * 8;
    const int fr1 = ((4 + lq) ^ (lm & 7)) * 8;
    const u16* a_rd = &As[(wrow + lm) * 64];
    const u16* b_rd = &Bs[(wcol + lm) * 64];

    for (int k0 = 0; k0 < k_len; k0 += 64) {
        #pragma unroll
        for (int i = 0; i < 4; ++i) {
            gload_lds16(a_src + k0 + (size_t)(i * 8) * kstride, a_dst + (i * 8) * 64);
            gload_lds16(b_src + k0 + (size_t)(i * 8) * kstride, b_dst + (i * 8) * 64);
        }
        __syncthreads();
        #pragma unroll
        for (int h = 0; h < 2; ++h) {
            const int fo = h ? fr1 : fr0;
            bf16x8 av[4], bv[4];
            #pragma unroll
            for (int m = 0; m < 4; ++m) av[m] = *(const bf16x8*)(a_rd + m * 16 * 64 + fo);
            #pragma unroll
            for (int n = 0; n < 4; ++n) bv[n] = *(const bf16x8*)(b_rd + n * 16 * 64 + fo);
            #pragma unroll
            for (int m = 0; m < 4; ++m)
                #pragma unroll
                for (int n = 0; n < 4; ++n)
                    acc[m][n] = __builtin_amdgcn_mfma_f32_16x16x32_bf16(av[m], bv[n], acc[m][n], 0, 0, 0);
        }
        __syncthreads();
    }

    float bz[4] = {0.f, 0.f, 0.f, 0.f};
    if (EPI != 3) {
        #pragma unroll
        for (int n = 0; n < 4; ++n) bz[n] = bias[col0 + wcol + n * 16 + lm];
    }

    if (EPI == 4 && col0 >= 2048) {
        // V part -> Vt[(b*16+h)*64 + d][2048]
        #pragma unroll
        for (int m = 0; m < 4; ++m) {
            int rbase = row0 + wrow + m * 16 + lq * 4;
            int b = rbase >> 11, s = rbase & 2047;
            #pragma unroll
            for (int n = 0; n < 4; ++n) {
                int c = col0 + wcol + n * 16 + lm - 2048;
                u16x4 pk = { f2bf(acc[m][n][0] + bz[n]), f2bf(acc[m][n][1] + bz[n]),
                             f2bf(acc[m][n][2] + bz[n]), f2bf(acc[m][n][3] + bz[n]) };
                *(u16x4*)&Vt[(size_t)((b * 16 + (c >> 6)) * 64 + (c & 63)) * 2048 + s] = pk;
            }
        }
        return;
    }

    u16* Cz = (u16*)Cout + (EPI == 3 ? (size_t)blockIdx.z * M * N : 0);
    #pragma unroll
    for (int m = 0; m < 4; ++m) {
        #pragma unroll
        for (int e = 0; e < 4; ++e) {
            int row = row0 + wrow + m * 16 + lq * 4 + e;
            #pragma unroll
            for (int n = 0; n < 4; ++n) {
                int col = col0 + wcol + n * 16 + lm;
                float v = acc[m][n][e] + bz[n];
                if (EPI == 1) v = v > 0.f ? v : NEG_SLOPE * v;
                Cz[(size_t)row * N + col] = f2bf(v);
            }
        }
    }
}

// ---------------------------------------------------------------------------
// Flash attention, bf16 MFMA. K/V staged via global_load_lds (XOR chunk
// swizzle) into double-buffered LDS, DMA for tile kt+1 issued at top of
// iter kt -> one barrier per key-tile. P and Q are wave-private (wave w
// writes AND reads rows w*16..+15) so the P round-trip needs no barrier.
// P stored stride-64 with the SAME XOR chunk swizzle as the staging
// (slot = chunk ^ (row&7)) -> total LDS 40960 B = exactly 4 blocks/CU.
// No-max exp2 softmax (scale folded into Q weights); row sums via ones-MFMA.
// ---------------------------------------------------------------------------
__global__ __launch_bounds__(256)
void attn_mfma(const u16* __restrict__ QKV, const u16* __restrict__ Vt,
               u16* __restrict__ ctx)
{
    __shared__ u16 QP[64 * 64];       // Q staged (swizzled); later P (swizzled)
    __shared__ u16 Kb[2][64 * 64];
    __shared__ u16 Vb[2][64 * 64];
    const int tid = threadIdx.x, w = tid >> 6, lane = tid & 63;
    const int lm = lane & 15, lq = lane >> 4;
    const int q0 = blockIdx.x * 64;
    const int bh = blockIdx.y;
    const int b  = bh >> 4, h = bh & 15;
    const size_t row_b = (size_t)b * SS;
    const int ccol = h * DKH;

    // staging geometry: wave w stages rows w*16..+15 (2 issues of 8 rows)
    const int r_i = lane >> 3;                 // 0..7
    const int csw = ((lane & 7) ^ r_i) * 8;    // swizzled chunk offset
    const u16* ksrc = QKV + (row_b + w * 16 + r_i) * 3072 + 1024 + ccol + csw;
    const u16* vsrc = Vt + ((size_t)bh * 64 + w * 16 + r_i) * SS + csw;
    const u16* qsrc = QKV + (row_b + q0 + w * 16 + r_i) * 3072 + ccol + csw;

    gload_lds16(qsrc,                    &QP[(w * 16) * 64]);
    gload_lds16(qsrc + (size_t)8 * 3072, &QP[(w * 16 + 8) * 64]);
    #pragma unroll
    for (int i = 0; i < 2; ++i) {
        gload_lds16(ksrc + (size_t)(i * 8) * 3072, &Kb[0][(w * 16 + i * 8) * 64]);
        gload_lds16(vsrc + (size_t)(i * 8) * SS,   &Vb[0][(w * 16 + i * 8) * 64]);
    }
    __syncthreads();   // drain DMA: Q/K0/V0 visible

    const int fr0 = (lq ^ (lm & 7)) * 8;
    const int fr1 = ((4 + lq) ^ (lm & 7)) * 8;
    bf16x8 aq0 = *(const bf16x8*)&QP[(w * 16 + lm) * 64 + fr0];
    bf16x8 aq1 = *(const bf16x8*)&QP[(w * 16 + lm) * 64 + fr1];
    __syncthreads();   // all waves hold Q in regs before P overwrites QP

    bf16x8 ones;
    #pragma unroll
    for (int j = 0; j < 8; ++j) ones[j] = (__bf16)1.0f;

    f32x4 o[4] = {};
    f32x4 lacc = {};

    for (int kt = 0; kt < SS / 64; ++kt) {
        const int cur = kt & 1;
        if (kt < SS / 64 - 1) {
            const int nxt = cur ^ 1;
            const size_t koff = (size_t)(kt + 1) * 64;
            #pragma unroll
            for (int i = 0; i < 2; ++i) {
                gload_lds16(ksrc + (koff + i * 8) * 3072, &Kb[nxt][(w * 16 + i * 8) * 64]);
                gload_lds16(vsrc + koff + (size_t)(i * 8) * SS, &Vb[nxt][(w * 16 + i * 8) * 64]);
            }
        }
        f32x4 s[4] = {};
        #pragma unroll
        for (int n = 0; n < 4; ++n) {
            bf16x8 bk0 = *(const bf16x8*)&Kb[cur][(n * 16 + lm) * 64 + fr0];
            bf16x8 bk1 = *(const bf16x8*)&Kb[cur][(n * 16 + lm) * 64 + fr1];
            s[n] = __builtin_amdgcn_mfma_f32_16x16x32_bf16(aq0, bk0, s[n], 0, 0, 0);
            s[n] = __builtin_amdgcn_mfma_f32_16x16x32_bf16(aq1, bk1, s[n], 0, 0, 0);
        }
        // P = 2^S, wave-private rows, stride-64 XOR-swizzled store:
        // value (row, col) -> QP[row*64 + ((col>>3)^(row&7))*8 + (col&7)]
        const int rb = lq * 4;              // row base within wave slab
        const int cw = lm & 7;              // within-chunk offset
        #pragma unroll
        for (int n = 0; n < 4; ++n) {
            const int cb = n * 2 + (lm >> 3);   // logical chunk of this col
            #pragma unroll
            for (int e = 0; e < 4; ++e) {
                float p = __builtin_exp2f(s[n][e]);
                const int row = w * 16 + rb + e;
                QP[row * 64 + ((cb ^ ((rb + e) & 7)) * 8) + cw] =
                    (u16)((__float_as_uint(p) + 0x8000u) >> 16);
            }
        }
        bf16x8 ap0 = *(const bf16x8*)&QP[(w * 16 + lm) * 64 + fr0];
        bf16x8 ap1 = *(const bf16x8*)&QP[(w * 16 + lm) * 64 + fr1];
        #pragma unroll
        for (int n = 0; n < 4; ++n) {
            bf16x8 bv0 = *(const bf16x8*)&Vb[cur][(n * 16 + lm) * 64 + fr0];
            bf16x8 bv1 = *(const bf16x8*)&Vb[cur][(n * 16 + lm) * 64 + fr1];
            o[n] = __builtin_amdgcn_mfma_f32_16x16x32_bf16(ap0, bv0, o[n], 0, 0, 0);
            o[n] = __builtin_amdgcn_mfma_f32_16x16x32_bf16(ap1, bv1, o[n], 0, 0, 0);
        }
        lacc = __builtin_amdgcn_mfma_f32_16x16x32_bf16(ap0, ones, lacc, 0, 0, 0);
        lacc = __builtin_amdgcn_mfma_f32_16x16x32_bf16(ap1, ones, lacc, 0, 0, 0);
        __syncthreads();   // all waves done with cur; nxt DMA drained
    }

    #pragma unroll
    for (int e = 0; e < 4; ++e) {
        float inv = 1.0f / lacc[e];
        int row = q0 + w * 16 + lq * 4 + e;
        u16* dst = ctx + (row_b + row) * D_MODEL + ccol;
        #pragma unroll
        for (int n = 0; n < 4; ++n)
            dst[n * 16 + lm] = f2bf(o[n][e] * inv);
    }
}

// ---------------------------------------------------------------------------
// out = LayerNorm(bf16 C0 + bf16 C1 + cbias + resid) * g + beta.
// ---------------------------------------------------------------------------
template<int OUTF32, int RESBF>
__global__ __launch_bounds__(256)
void add_ln(const u16* __restrict__ C0, const u16* __restrict__ C1,
            const float* __restrict__ cbias, const void* __restrict__ resid,
            const float* __restrict__ g, const float* __restrict__ beta,
            float* __restrict__ outf, u16* __restrict__ outb)
{
    __shared__ float red[8];
    const int row = blockIdx.x;
    const int tid = threadIdx.x;
    u16x4 p0 = ((const u16x4*)(C0 + (size_t)row * D_MODEL))[tid];
    u16x4 p1 = ((const u16x4*)(C1 + (size_t)row * D_MODEL))[tid];
    float4 cb = ((const float4*)cbias)[tid];
    float4 rr;
    if (RESBF) {
        u16x4 rb = ((const u16x4*)((const u16*)resid + (size_t)row * D_MODEL))[tid];
        rr = { bf2f(rb.x), bf2f(rb.y), bf2f(rb.z), bf2f(rb.w) };
    } else {
        rr = ((const float4*)((const float*)resid + (size_t)row * D_MODEL))[tid];
    }
    float4 v = { bf2f(p0.x) + bf2f(p1.x) + cb.x + rr.x,
                 bf2f(p0.y) + bf2f(p1.y) + cb.y + rr.y,
                 bf2f(p0.z) + bf2f(p1.z) + cb.z + rr.z,
                 bf2f(p0.w) + bf2f(p1.w) + cb.w + rr.w };
    float s  = v.x + v.y + v.z + v.w;
    float sq = v.x*v.x + v.y*v.y + v.z*v.z + v.w*v.w;
    #pragma unroll
    for (int off = 32; off > 0; off >>= 1) {
        s  += __shfl_down(s,  off, 64);
        sq += __shfl_down(sq, off, 64);
    }
    const int wv = tid >> 6;
    if ((tid & 63) == 0) { red[wv] = s; red[4 + wv] = sq; }
    __syncthreads();
    float st  = red[0] + red[1] + red[2] + red[3];
    float sqt = red[4] + red[5] + red[6] + red[7];
    float mu   = st * (1.0f / D_MODEL);
    float var  = sqt * (1.0f / D_MODEL) - mu * mu;
    float rstd = rsqrtf(var + EPSLN);
    float4 gv = ((const float4*)g)[tid];
    float4 bt = ((const float4*)beta)[tid];
    float4 ov;
    ov.x = (v.x - mu) * rstd * gv.x + bt.x;
    ov.y = (v.y - mu) * rstd * gv.y + bt.y;
    ov.z = (v.z - mu) * rstd * gv.z + bt.z;
    ov.w = (v.w - mu) * rstd * gv.w + bt.w;
    if (OUTF32) {
        ((float4*)(outf + (size_t)row * D_MODEL))[tid] = ov;
    } else {
        u16x4 ob = { f2bf(ov.x), f2bf(ov.y), f2bf(ov.z), f2bf(ov.w) };
        ((u16x4*)(outb + (size_t)row * D_MODEL))[tid] = ob;
    }
}

// ---------------------------------------------------------------------------
extern "C" void kernel_launch(void* const* d_in, const int* in_sizes, int n_in,
                              void* d_out, int out_size, void* d_ws, size_t ws_size,
                              hipStream_t stream) {
    const float* x     = (const float*)d_in[0];
    const float* wq    = (const float*)d_in[1];
    const float* bq    = (const float*)d_in[2];
    const float* wk    = (const float*)d_in[3];
    const float* bk    = (const float*)d_in[4];
    const float* wv    = (const float*)d_in[5];
    const float* bv    = (const float*)d_in[6];
    const float* wo    = (const float*)d_in[7];
    const float* bo    = (const float*)d_in[8];
    const float* g1    = (const float*)d_in[9];
    const float* b1    = (const float*)d_in[10];
    const float* w_ff1 = (const float*)d_in[11];
    const float* b_ff1 = (const float*)d_in[12];
    const float* w_ff2 = (const float*)d_in[13];
    const float* b_ff2 = (const float*)d_in[14];
    const float* g2    = (const float*)d_in[15];
    const float* b2    = (const float*)d_in[16];
    float* out = (float*)d_out;

    const float qscale = 0.18033688011112042f;   // log2(e) / sqrt(DK)

    char* W = (char*)d_ws;
    u16*   x_bf    = (u16*)(W + 0);             // 8.4 MB (later: ctx)
    u16*   wqkvT   = (u16*)(W + 8388608);       // 6.3 MB
    u16*   woT     = (u16*)(W + 14680064);      // 2.1 MB
    u16*   wff1T   = (u16*)(W + 16777216);      // 8.4 MB
    u16*   wff2T   = (u16*)(W + 25165824);      // 8.4 MB
    u16*   QKV     = (u16*)(W + 33554432);      // 25.2 MB (later: ff1)
    u16*   VtG     = (u16*)(W + 58720256);      // 8.4 MB
    u16*   C0      = (u16*)(W + 67108864);      // 8.4 MB (split-K partial 0)
    u16*   C1      = (u16*)(W + 75497472);      // 8.4 MB (split-K partial 1)
    u16*   h_bf    = (u16*)(W + 83886080);      // 8.4 MB
    float* qkv_bias= (float*)(W + 92274688);    // 12 KB
    u16*   ctx     = x_bf;
    u16*   ff1_bf  = QKV;

    dim3 blk(256);
    prep<<<7180, blk, 0, stream>>>(x, x_bf, wq, wk, wv, wo, w_ff1, w_ff2,
                                   wqkvT, woT, wff1T, wff2T,
                                   bq, bk, bv, qkv_bias, qscale);
    gemm_bf16<4><<<dim3(24, 32, 1), blk, 0, stream>>>(x_bf, wqkvT, qkv_bias, QKV, VtG, MTOT, 3072, 1024, 1024);
    attn_mfma<<<dim3(32, 32), blk, 0, stream>>>(QKV, VtG, ctx);
    gemm_bf16<3><<<dim3(8, 32, 2), blk, 0, stream>>>(ctx, woT, nullptr, C0, nullptr, MTOT, 1024, 512, 1024);
    add_ln<0, 0><<<MTOT, blk, 0, stream>>>(C0, C1, bo, x, g1, b1, nullptr, h_bf);
    gemm_bf16<1><<<dim3(32, 32, 1), blk, 0, stream>>>(h_bf, wff1T, b_ff1, ff1_bf, nullptr, MTOT, DFF_, 1024, 1024);
    gemm_bf16<3><<<dim3(8, 32, 2), blk, 0, stream>>>(ff1_bf, wff2T, nullptr, C0, nullptr, MTOT, 1024, 2048, 4096);
    add_ln<1, 1><<<MTOT, blk, 0, stream>>>(C0, C1, b_ff2, h_bf, g2, b2, out, nullptr);
}